// Round 1
// baseline (2291.658 us; speedup 1.0000x reference)
//
#include <hip/hip_runtime.h>
#include <hip/hip_bf16.h>
#include <math.h>

#define N_NODES 50000
#define N_EDGES 800000
#define E_TOT   850000   // incl. self loops
#define IN_DIM  128
#define HID     32
#define HEADS   4
#define D1      128      // HEADS*HID
#define OUT_DIM 40
#define NEG_SLOPE 0.2f

// ---- monotone float<->uint mapping for atomicMax on floats ----
__device__ __forceinline__ unsigned fmap(float f){
  unsigned u = __float_as_uint(f);
  return (u & 0x80000000u) ? ~u : (u | 0x80000000u);
}
__device__ __forceinline__ float funmap(unsigned u){
  unsigned b = (u & 0x80000000u) ? (u ^ 0x80000000u) : ~u;
  return __uint_as_float(b);
}

// ================= GEMM1: h1 = x @ W1, fused alpha_src/dst =================
__global__ __launch_bounds__(256) void gemm1(
    const float* __restrict__ x, const float* __restrict__ W,
    const float* __restrict__ as_v, const float* __restrict__ ad_v,
    float* __restrict__ h1, float* __restrict__ asrc, float* __restrict__ adst)
{
  __shared__ float xs[32][IN_DIM];
  const int nb = blockIdx.x * 32;
  const int t  = threadIdx.x;
  for (int i = t; i < 32 * IN_DIM; i += 256) {
    int r = i >> 7, k = i & 127;
    int n = nb + r;
    xs[r][k] = (n < N_NODES) ? x[n * IN_DIM + k] : 0.f;
  }
  __syncthreads();
  const int col = t & 127;
  const int rbase = (t >> 7) * 16;
  float acc[16];
#pragma unroll
  for (int r = 0; r < 16; ++r) acc[r] = 0.f;
  for (int k = 0; k < IN_DIM; ++k) {
    float w = W[k * D1 + col];
#pragma unroll
    for (int r = 0; r < 16; ++r) acc[r] += xs[rbase + r][k] * w;
  }
  const int head = col >> 5, cc = col & 31;
  const float a_s = as_v[head * HID + cc];
  const float a_d = ad_v[head * HID + cc];
#pragma unroll
  for (int r = 0; r < 16; ++r) {
    int n = nb + rbase + r;
    if (n < N_NODES) h1[n * D1 + col] = acc[r];
    float cs = acc[r] * a_s, cd = acc[r] * a_d;
#pragma unroll
    for (int off = 16; off >= 1; off >>= 1) {
      cs += __shfl_xor(cs, off, 64);
      cd += __shfl_xor(cd, off, 64);
    }
    if (cc == 0 && n < N_NODES) {
      asrc[n * HEADS + head] = cs;
      adst[n * HEADS + head] = cd;
    }
  }
}

// ================= init kernels =================
__global__ void init_l1(unsigned* __restrict__ maxb, float* __restrict__ sumb,
                        float* __restrict__ out1)
{
  int i = blockIdx.x * blockDim.x + threadIdx.x;
  if (i < N_NODES * D1) out1[i] = 0.f;
  if (i < N_NODES * HEADS) { maxb[i] = 0u; sumb[i] = 0.f; }
}
__global__ void init_l2(const float* __restrict__ b2, unsigned* __restrict__ maxb,
                        float* __restrict__ sumb, float* __restrict__ out)
{
  int i = blockIdx.x * blockDim.x + threadIdx.x;
  if (i < N_NODES * OUT_DIM) out[i] = b2[i % OUT_DIM];
  if (i < N_NODES) { maxb[i] = 0u; sumb[i] = 0.f; }
}

// ================= layer-1 edge passes =================
__global__ void passA1(const int* __restrict__ ei, const float* __restrict__ asrc,
                       const float* __restrict__ adst, float* __restrict__ lbuf,
                       unsigned* __restrict__ maxb)
{
  int idx = blockIdx.x * blockDim.x + threadIdx.x;
  if (idx >= E_TOT * HEADS) return;
  int e = idx >> 2, h = idx & 3;
  int s, d;
  if (e < N_EDGES) { s = ei[e]; d = ei[N_EDGES + e]; }
  else             { s = d = e - N_EDGES; }
  float v = asrc[s * HEADS + h] + adst[d * HEADS + h];
  float le = v > 0.f ? v : NEG_SLOPE * v;
  lbuf[idx] = le;
  atomicMax(maxb + d * HEADS + h, fmap(le));
}

__global__ void passB1(const int* __restrict__ ei, const unsigned* __restrict__ maxb,
                       float* __restrict__ lbuf, float* __restrict__ sumb)
{
  int idx = blockIdx.x * blockDim.x + threadIdx.x;
  if (idx >= E_TOT * HEADS) return;
  int e = idx >> 2, h = idx & 3;
  int d = (e < N_EDGES) ? ei[N_EDGES + e] : e - N_EDGES;
  float ev = __expf(lbuf[idx] - funmap(maxb[d * HEADS + h]));
  lbuf[idx] = ev;
  atomicAdd(sumb + d * HEADS + h, ev);
}

__global__ void passC1(const int* __restrict__ ei, const float* __restrict__ lbuf,
                       const float* __restrict__ sumb, const float* __restrict__ h1,
                       float* __restrict__ out1)
{
  int idx = blockIdx.x * blockDim.x + threadIdx.x;
  if (idx >= E_TOT * 32) return;
  int e = idx >> 5;
  int c = (idx & 31) * 4;
  int h = c >> 5;
  int s, d;
  if (e < N_EDGES) { s = ei[e]; d = ei[N_EDGES + e]; }
  else             { s = d = e - N_EDGES; }
  float coef = lbuf[e * HEADS + h] / sumb[d * HEADS + h];
  const float4 hv = *reinterpret_cast<const float4*>(h1 + s * D1 + c);
  float* o = out1 + d * D1 + c;
  atomicAdd(o + 0, hv.x * coef);
  atomicAdd(o + 1, hv.y * coef);
  atomicAdd(o + 2, hv.z * coef);
  atomicAdd(o + 3, hv.w * coef);
}

// ================= GEMM2: h2 = relu(out1+b1) @ W2, fused alpha2 =================
__global__ __launch_bounds__(256) void gemm2(
    const float* __restrict__ agg1, const float* __restrict__ b1,
    const float* __restrict__ W2, const float* __restrict__ as2,
    const float* __restrict__ ad2, float* __restrict__ h2,
    float* __restrict__ asrc2, float* __restrict__ adst2)
{
  __shared__ float zs[32][IN_DIM];
  const int nb = blockIdx.x * 32;
  const int t  = threadIdx.x;
  for (int i = t; i < 32 * IN_DIM; i += 256) {
    int r = i >> 7, k = i & 127;
    int n = nb + r;
    float v = (n < N_NODES) ? agg1[n * IN_DIM + k] + b1[k] : 0.f;
    zs[r][k] = v > 0.f ? v : 0.f;
  }
  __syncthreads();
  const int col = t & 63;
  const int rbase = (t >> 6) * 8;
  const bool valid = col < OUT_DIM;
  const int colc = valid ? col : (OUT_DIM - 1);
  float acc[8];
#pragma unroll
  for (int r = 0; r < 8; ++r) acc[r] = 0.f;
  for (int k = 0; k < IN_DIM; ++k) {
    float w = W2[k * OUT_DIM + colc];
#pragma unroll
    for (int r = 0; r < 8; ++r) acc[r] += zs[rbase + r][k] * w;
  }
  const float a_s = valid ? as2[col] : 0.f;
  const float a_d = valid ? ad2[col] : 0.f;
#pragma unroll
  for (int r = 0; r < 8; ++r) {
    int n = nb + rbase + r;
    float cs = acc[r] * a_s, cd = acc[r] * a_d;
#pragma unroll
    for (int off = 32; off >= 1; off >>= 1) {
      cs += __shfl_xor(cs, off, 64);
      cd += __shfl_xor(cd, off, 64);
    }
    if (n < N_NODES) {
      if (valid) h2[n * OUT_DIM + col] = acc[r];
      if (col == 0) { asrc2[n] = cs; adst2[n] = cd; }
    }
  }
}

// ================= layer-2 edge passes =================
__global__ void passA2(const int* __restrict__ ei, const float* __restrict__ asrc,
                       const float* __restrict__ adst, float* __restrict__ lbuf,
                       unsigned* __restrict__ maxb)
{
  int e = blockIdx.x * blockDim.x + threadIdx.x;
  if (e >= E_TOT) return;
  int s, d;
  if (e < N_EDGES) { s = ei[e]; d = ei[N_EDGES + e]; }
  else             { s = d = e - N_EDGES; }
  float v = asrc[s] + adst[d];
  float le = v > 0.f ? v : NEG_SLOPE * v;
  lbuf[e] = le;
  atomicMax(maxb + d, fmap(le));
}

__global__ void passB2(const int* __restrict__ ei, const unsigned* __restrict__ maxb,
                       float* __restrict__ lbuf, float* __restrict__ sumb)
{
  int e = blockIdx.x * blockDim.x + threadIdx.x;
  if (e >= E_TOT) return;
  int d = (e < N_EDGES) ? ei[N_EDGES + e] : e - N_EDGES;
  float ev = __expf(lbuf[e] - funmap(maxb[d]));
  lbuf[e] = ev;
  atomicAdd(sumb + d, ev);
}

__global__ void passC2(const int* __restrict__ ei, const float* __restrict__ lbuf,
                       const float* __restrict__ sumb, const float* __restrict__ h2,
                       float* __restrict__ out)
{
  int idx = blockIdx.x * blockDim.x + threadIdx.x;
  if (idx >= E_TOT * 10) return;
  int e = idx / 10;
  int c = (idx - e * 10) * 4;
  int s, d;
  if (e < N_EDGES) { s = ei[e]; d = ei[N_EDGES + e]; }
  else             { s = d = e - N_EDGES; }
  float coef = lbuf[e] / sumb[d];
  const float4 hv = *reinterpret_cast<const float4*>(h2 + s * OUT_DIM + c);
  float* o = out + d * OUT_DIM + c;
  atomicAdd(o + 0, hv.x * coef);
  atomicAdd(o + 1, hv.y * coef);
  atomicAdd(o + 2, hv.z * coef);
  atomicAdd(o + 3, hv.w * coef);
}

// ================= launch =================
extern "C" void kernel_launch(void* const* d_in, const int* in_sizes, int n_in,
                              void* d_out, int out_size, void* d_ws, size_t ws_size,
                              hipStream_t stream)
{
  const float* x    = (const float*)d_in[0];
  const int*   ei   = (const int*)  d_in[1];
  const float* W1   = (const float*)d_in[2];
  const float* as1  = (const float*)d_in[3];
  const float* ad1  = (const float*)d_in[4];
  const float* b1   = (const float*)d_in[5];
  const float* W2   = (const float*)d_in[6];
  const float* as2  = (const float*)d_in[7];
  const float* ad2  = (const float*)d_in[8];
  const float* b2   = (const float*)d_in[9];
  float* out = (float*)d_out;

  float* ws = (float*)d_ws;
  float*    h1    = ws +  0;            // N*128
  float*    out1  = ws +  6400000;      // N*128
  float*    h2    = ws + 12800000;      // N*40
  float*    asrc1 = ws + 14800000;      // N*4
  float*    adst1 = ws + 15000000;
  unsigned* maxb1 = (unsigned*)(ws + 15200000);
  float*    sumb1 = ws + 15400000;
  float*    asrc2 = ws + 15600000;      // N
  float*    adst2 = ws + 15650000;
  unsigned* maxb2 = (unsigned*)(ws + 15700000);
  float*    sumb2 = ws + 15750000;
  float*    lbuf1 = ws + 15800000;      // E_TOT*4
  float*    lbuf2 = ws + 19200000;      // E_TOT

  const int B = 256;
  // layer 1
  gemm1<<<(N_NODES + 31) / 32, B, 0, stream>>>(x, W1, as1, ad1, h1, asrc1, adst1);
  init_l1<<<(N_NODES * D1 + B - 1) / B, B, 0, stream>>>(maxb1, sumb1, out1);
  passA1<<<(E_TOT * HEADS + B - 1) / B, B, 0, stream>>>(ei, asrc1, adst1, lbuf1, maxb1);
  passB1<<<(E_TOT * HEADS + B - 1) / B, B, 0, stream>>>(ei, maxb1, lbuf1, sumb1);
  passC1<<<(E_TOT * 32 + B - 1) / B, B, 0, stream>>>(ei, lbuf1, sumb1, h1, out1);
  // layer 2
  gemm2<<<(N_NODES + 31) / 32, B, 0, stream>>>(out1, b1, W2, as2, ad2, h2, asrc2, adst2);
  init_l2<<<(N_NODES * OUT_DIM + B - 1) / B, B, 0, stream>>>(b2, maxb2, sumb2, out);
  passA2<<<(E_TOT + B - 1) / B, B, 0, stream>>>(ei, asrc2, adst2, lbuf2, maxb2);
  passB2<<<(E_TOT + B - 1) / B, B, 0, stream>>>(ei, maxb2, lbuf2, sumb2);
  passC2<<<(E_TOT * 10 + B - 1) / B, B, 0, stream>>>(ei, lbuf2, sumb2, h2, out);
}

// Round 3
// 593.005 us; speedup vs baseline: 3.8645x; 3.8645x over previous
//
#include <hip/hip_runtime.h>
#include <hip/hip_bf16.h>
#include <math.h>

#define N_NODES 50000
#define N_EDGES 800000
#define E_TOT   850000   // incl. self loops
#define IN_DIM  128
#define HID     32
#define HEADS   4
#define D1      128      // HEADS*HID
#define OUT_DIM 40
#define NEG_SLOPE 0.2f

// ================= GEMM1: h1 = x @ W1, fused alpha_src/dst =================
__global__ __launch_bounds__(256) void gemm1(
    const float* __restrict__ x, const float* __restrict__ W,
    const float* __restrict__ as_v, const float* __restrict__ ad_v,
    float* __restrict__ h1, float* __restrict__ asrc, float* __restrict__ adst)
{
  __shared__ float xs[32][IN_DIM];
  const int nb = blockIdx.x * 32;
  const int t  = threadIdx.x;
  for (int i = t; i < 32 * IN_DIM; i += 256) {
    int r = i >> 7, k = i & 127;
    int n = nb + r;
    xs[r][k] = (n < N_NODES) ? x[n * IN_DIM + k] : 0.f;
  }
  __syncthreads();
  const int col = t & 127;
  const int rbase = (t >> 7) * 16;
  float acc[16];
#pragma unroll
  for (int r = 0; r < 16; ++r) acc[r] = 0.f;
  for (int k = 0; k < IN_DIM; ++k) {
    float w = W[k * D1 + col];
#pragma unroll
    for (int r = 0; r < 16; ++r) acc[r] += xs[rbase + r][k] * w;
  }
  const int head = col >> 5, cc = col & 31;
  const float a_s = as_v[head * HID + cc];
  const float a_d = ad_v[head * HID + cc];
#pragma unroll
  for (int r = 0; r < 16; ++r) {
    int n = nb + rbase + r;
    if (n < N_NODES) h1[n * D1 + col] = acc[r];
    float cs = acc[r] * a_s, cd = acc[r] * a_d;
#pragma unroll
    for (int off = 16; off >= 1; off >>= 1) {
      cs += __shfl_xor(cs, off, 64);
      cd += __shfl_xor(cd, off, 64);
    }
    if (cc == 0 && n < N_NODES) {
      asrc[n * HEADS + head] = cs;
      adst[n * HEADS + head] = cd;
    }
  }
}

// ================= CSR build =================
__global__ void init_deg(int* __restrict__ deg)
{
  int i = blockIdx.x * blockDim.x + threadIdx.x;
  if (i < N_NODES) deg[i] = 0;
}

__global__ void count_deg(const int* __restrict__ ei, int* __restrict__ deg)
{
  int e = blockIdx.x * blockDim.x + threadIdx.x;
  if (e >= E_TOT) return;
  int d = (e < N_EDGES) ? ei[N_EDGES + e] : e - N_EDGES;
  atomicAdd(deg + d, 1);
}

__global__ __launch_bounds__(1024) void scan_deg(
    const int* __restrict__ deg, int* __restrict__ row_off, int* __restrict__ cursor)
{
  __shared__ int sums[1024];
  const int t = threadIdx.x;
  const int CH = 49;  // 1024*49 >= 50000
  const int base = t * CH;
  int local = 0;
  for (int i = 0; i < CH; ++i) {
    int idx = base + i;
    if (idx < N_NODES) local += deg[idx];
  }
  sums[t] = local;
  __syncthreads();
  for (int off = 1; off < 1024; off <<= 1) {
    int add = (t >= off) ? sums[t - off] : 0;
    __syncthreads();
    sums[t] += add;
    __syncthreads();
  }
  int run = sums[t] - local;  // exclusive prefix
  for (int i = 0; i < CH; ++i) {
    int idx = base + i;
    if (idx < N_NODES) {
      row_off[idx] = run;
      cursor[idx] = run;
      run += deg[idx];
    }
  }
  if (t == 0) row_off[N_NODES] = E_TOT;
}

__global__ void scatter_csr(const int* __restrict__ ei, int* __restrict__ cursor,
                            int* __restrict__ csr_src)
{
  int e = blockIdx.x * blockDim.x + threadIdx.x;
  if (e >= E_TOT) return;
  int s, d;
  if (e < N_EDGES) { s = ei[e]; d = ei[N_EDGES + e]; }
  else             { s = d = e - N_EDGES; }
  int pos = atomicAdd(cursor + d, 1);
  csr_src[pos] = s;
}

// ============ agg1: per-node softmax + aggregate + bias + relu ============
__global__ __launch_bounds__(256) void agg1(
    const int* __restrict__ row_off, const int* __restrict__ csr_src,
    const float* __restrict__ asrc, const float* __restrict__ adst,
    const float* __restrict__ h1, const float* __restrict__ b1,
    float* __restrict__ z)
{
  int n = blockIdx.x * 4 + (threadIdx.x >> 6);
  if (n >= N_NODES) return;
  const int lane = threadIdx.x & 63;
  const int start = row_off[n], end = row_off[n + 1];
  const int h = lane & 3;
  const float adst_h = adst[n * HEADS + h];
  // phase 1: per-head max of asrc (leaky-relu monotone => max commutes)
  float vmax = -1e30f;
  for (int i = start + (lane >> 2); i < end; i += 16)
    vmax = fmaxf(vmax, asrc[csr_src[i] * HEADS + h]);
#pragma unroll
  for (int off = 4; off < 64; off <<= 1)
    vmax = fmaxf(vmax, __shfl_xor(vmax, off, 64));
  float v = vmax + adst_h;
  const float mle = v > 0.f ? v : NEG_SLOPE * v;
  // phase 2: per-head sum of exp
  float ssum = 0.f;
  for (int i = start + (lane >> 2); i < end; i += 16) {
    float tv = asrc[csr_src[i] * HEADS + h] + adst_h;
    float le = tv > 0.f ? tv : NEG_SLOPE * tv;
    ssum += __expf(le - mle);
  }
#pragma unroll
  for (int off = 4; off < 64; off <<= 1)
    ssum += __shfl_xor(ssum, off, 64);
  // broadcast this lane's two heads (lane -> channels lane, lane+64)
  const int hlo = lane >> 5, hhi = 2 + (lane >> 5);
  const float m_lo = __shfl(mle, hlo, 64);
  const float m_hi = __shfl(mle, hhi, 64);
  const float is_lo = 1.f / __shfl(ssum, hlo, 64);
  const float is_hi = 1.f / __shfl(ssum, hhi, 64);
  const float ad_lo = adst[n * HEADS + hlo];
  const float ad_hi = adst[n * HEADS + hhi];
  float acc0 = 0.f, acc1 = 0.f;
  for (int i = start; i < end; ++i) {
    int s = csr_src[i];
    float t0 = asrc[s * HEADS + hlo] + ad_lo;
    float t1 = asrc[s * HEADS + hhi] + ad_hi;
    t0 = t0 > 0.f ? t0 : NEG_SLOPE * t0;
    t1 = t1 > 0.f ? t1 : NEG_SLOPE * t1;
    float a0 = __expf(t0 - m_lo) * is_lo;
    float a1 = __expf(t1 - m_hi) * is_hi;
    acc0 += a0 * h1[s * D1 + lane];
    acc1 += a1 * h1[s * D1 + 64 + lane];
  }
  float r0 = acc0 + b1[lane];
  float r1 = acc1 + b1[64 + lane];
  z[n * D1 + lane]      = r0 > 0.f ? r0 : 0.f;
  z[n * D1 + 64 + lane] = r1 > 0.f ? r1 : 0.f;
}

// ================= GEMM2: h2 = z @ W2, fused alpha2 =================
__global__ __launch_bounds__(256) void gemm2(
    const float* __restrict__ z, const float* __restrict__ W2,
    const float* __restrict__ as2, const float* __restrict__ ad2,
    float* __restrict__ h2, float* __restrict__ asrc2, float* __restrict__ adst2)
{
  __shared__ float zs[32][IN_DIM];
  const int nb = blockIdx.x * 32;
  const int t  = threadIdx.x;
  for (int i = t; i < 32 * IN_DIM; i += 256) {
    int r = i >> 7, k = i & 127;
    int n = nb + r;
    zs[r][k] = (n < N_NODES) ? z[n * IN_DIM + k] : 0.f;
  }
  __syncthreads();
  const int col = t & 63;
  const int rbase = (t >> 6) * 8;
  const bool valid = col < OUT_DIM;
  const int colc = valid ? col : (OUT_DIM - 1);
  float acc[8];
#pragma unroll
  for (int r = 0; r < 8; ++r) acc[r] = 0.f;
  for (int k = 0; k < IN_DIM; ++k) {
    float w = W2[k * OUT_DIM + colc];
#pragma unroll
    for (int r = 0; r < 8; ++r) acc[r] += zs[rbase + r][k] * w;
  }
  const float a_s = valid ? as2[col] : 0.f;
  const float a_d = valid ? ad2[col] : 0.f;
#pragma unroll
  for (int r = 0; r < 8; ++r) {
    int n = nb + rbase + r;
    float cs = acc[r] * a_s, cd = acc[r] * a_d;
#pragma unroll
    for (int off = 32; off >= 1; off >>= 1) {
      cs += __shfl_xor(cs, off, 64);
      cd += __shfl_xor(cd, off, 64);
    }
    if (n < N_NODES) {
      if (valid) h2[n * OUT_DIM + col] = acc[r];
      if (col == 0) { asrc2[n] = cs; adst2[n] = cd; }
    }
  }
}

// ============ agg2: per-node softmax + aggregate + b2 -> out ============
__global__ __launch_bounds__(256) void agg2(
    const int* __restrict__ row_off, const int* __restrict__ csr_src,
    const float* __restrict__ asrc, const float* __restrict__ adst,
    const float* __restrict__ h2, const float* __restrict__ b2,
    float* __restrict__ out)
{
  int n = blockIdx.x * 4 + (threadIdx.x >> 6);
  if (n >= N_NODES) return;
  const int lane = threadIdx.x & 63;
  const int start = row_off[n], end = row_off[n + 1];
  const float adstn = adst[n];
  float vmax = -1e30f;
  for (int i = start + lane; i < end; i += 64)
    vmax = fmaxf(vmax, asrc[csr_src[i]]);
#pragma unroll
  for (int off = 1; off < 64; off <<= 1)
    vmax = fmaxf(vmax, __shfl_xor(vmax, off, 64));
  float v = vmax + adstn;
  const float mle = v > 0.f ? v : NEG_SLOPE * v;
  float ssum = 0.f;
  for (int i = start + lane; i < end; i += 64) {
    float t = asrc[csr_src[i]] + adstn;
    float le = t > 0.f ? t : NEG_SLOPE * t;
    ssum += __expf(le - mle);
  }
#pragma unroll
  for (int off = 1; off < 64; off <<= 1)
    ssum += __shfl_xor(ssum, off, 64);
  const float inv = 1.f / ssum;
  const bool valid = lane < OUT_DIM;
  float acc = 0.f;
  for (int i = start; i < end; ++i) {
    int s = csr_src[i];
    float t = asrc[s] + adstn;
    t = t > 0.f ? t : NEG_SLOPE * t;
    float a = __expf(t - mle) * inv;
    if (valid) acc += a * h2[s * OUT_DIM + lane];
  }
  if (valid) out[n * OUT_DIM + lane] = acc + b2[lane];
}

// ================= launch =================
extern "C" void kernel_launch(void* const* d_in, const int* in_sizes, int n_in,
                              void* d_out, int out_size, void* d_ws, size_t ws_size,
                              hipStream_t stream)
{
  const float* x    = (const float*)d_in[0];
  const int*   ei   = (const int*)  d_in[1];
  const float* W1   = (const float*)d_in[2];
  const float* as1  = (const float*)d_in[3];
  const float* ad1  = (const float*)d_in[4];
  const float* b1   = (const float*)d_in[5];
  const float* W2   = (const float*)d_in[6];
  const float* as2  = (const float*)d_in[7];
  const float* ad2  = (const float*)d_in[8];
  const float* b2   = (const float*)d_in[9];
  float* out = (float*)d_out;

  float* ws = (float*)d_ws;
  float* h1    = ws +  0;        // N*128
  float* z     = ws +  6400000;  // N*128 (relu(agg1+b1))
  float* h2    = ws + 12800000;  // N*40
  float* asrc1 = ws + 14800000;  // N*4
  float* adst1 = ws + 15000000;  // N*4
  float* asrc2 = ws + 15200000;  // N
  float* adst2 = ws + 15250000;  // N
  int* deg     = (int*)(ws + 15300000);  // N
  int* row_off = (int*)(ws + 15350000);  // N+1
  int* cursor  = (int*)(ws + 15410000);  // N
  int* csr_src = (int*)(ws + 15460000);  // E_TOT

  const int B = 256;
  // CSR build (by destination)
  init_deg<<<(N_NODES + B - 1) / B, B, 0, stream>>>(deg);
  count_deg<<<(E_TOT + B - 1) / B, B, 0, stream>>>(ei, deg);
  scan_deg<<<1, 1024, 0, stream>>>(deg, row_off, cursor);
  scatter_csr<<<(E_TOT + B - 1) / B, B, 0, stream>>>(ei, cursor, csr_src);
  // layer 1
  gemm1<<<(N_NODES + 31) / 32, B, 0, stream>>>(x, W1, as1, ad1, h1, asrc1, adst1);
  agg1<<<(N_NODES + 3) / 4, B, 0, stream>>>(row_off, csr_src, asrc1, adst1, h1, b1, z);
  // layer 2
  gemm2<<<(N_NODES + 31) / 32, B, 0, stream>>>(z, W2, as2, ad2, h2, asrc2, adst2);
  agg2<<<(N_NODES + 3) / 4, B, 0, stream>>>(row_off, csr_src, asrc2, adst2, h2, b2, out);
}

// Round 5
// 460.475 us; speedup vs baseline: 4.9767x; 1.2878x over previous
//
#include <hip/hip_runtime.h>
#include <hip/hip_bf16.h>
#include <math.h>

#define N_NODES 50000
#define N_EDGES 800000
#define E_TOT   850000   // incl. self loops
#define IN_DIM  128
#define HID     32
#define HEADS   4
#define D1      128      // HEADS*HID
#define OUT_DIM 40
#define NEG_SLOPE 0.2f

#define SCAN_TILE 1024
#define SCAN_NB   ((N_NODES + SCAN_TILE - 1) / SCAN_TILE)   // 49

// ================= GEMM1: h1 = x @ W1, fused alpha_src/dst =================
// 4 rows x 4 cols register tile per thread; float4 LDS reads.
__global__ __launch_bounds__(256) void gemm1(
    const float* __restrict__ x, const float* __restrict__ W,
    const float* __restrict__ as_v, const float* __restrict__ ad_v,
    float* __restrict__ h1, float* __restrict__ asrc, float* __restrict__ adst)
{
  __shared__ float xs[32][IN_DIM];
  const int nb = blockIdx.x * 32;
  const int t  = threadIdx.x;
  for (int i = t; i < 32 * (IN_DIM / 4); i += 256) {
    int r = i >> 5, k4 = (i & 31) * 4;
    int n = nb + r;
    float4 v = (n < N_NODES) ? *reinterpret_cast<const float4*>(x + (size_t)n * IN_DIM + k4)
                             : make_float4(0.f, 0.f, 0.f, 0.f);
    *reinterpret_cast<float4*>(&xs[r][k4]) = v;
  }
  __syncthreads();
  const int ct = t & 31, col0 = ct * 4;
  const int rt = t >> 5, rbase = rt * 4;
  float acc[4][4];
#pragma unroll
  for (int r = 0; r < 4; ++r)
#pragma unroll
    for (int c = 0; c < 4; ++c) acc[r][c] = 0.f;

  for (int k = 0; k < IN_DIM; k += 4) {
    float4 xv[4];
#pragma unroll
    for (int r = 0; r < 4; ++r)
      xv[r] = *reinterpret_cast<const float4*>(&xs[rbase + r][k]);
    float4 wv[4];
#pragma unroll
    for (int kk = 0; kk < 4; ++kk)
      wv[kk] = *reinterpret_cast<const float4*>(W + (size_t)(k + kk) * D1 + col0);
#pragma unroll
    for (int r = 0; r < 4; ++r) {
      acc[r][0] += xv[r].x * wv[0].x + xv[r].y * wv[1].x + xv[r].z * wv[2].x + xv[r].w * wv[3].x;
      acc[r][1] += xv[r].x * wv[0].y + xv[r].y * wv[1].y + xv[r].z * wv[2].y + xv[r].w * wv[3].y;
      acc[r][2] += xv[r].x * wv[0].z + xv[r].y * wv[1].z + xv[r].z * wv[2].z + xv[r].w * wv[3].z;
      acc[r][3] += xv[r].x * wv[0].w + xv[r].y * wv[1].w + xv[r].z * wv[2].w + xv[r].w * wv[3].w;
    }
  }

  const int head = col0 >> 5;           // 4 consecutive cols share a head
  const int cc0  = col0 & 31;
  const float4 asv = *reinterpret_cast<const float4*>(as_v + head * HID + cc0);
  const float4 adv = *reinterpret_cast<const float4*>(ad_v + head * HID + cc0);
#pragma unroll
  for (int r = 0; r < 4; ++r) {
    int n = nb + rbase + r;
    bool ok = n < N_NODES;
    if (ok) {
      float4 o = make_float4(acc[r][0], acc[r][1], acc[r][2], acc[r][3]);
      *reinterpret_cast<float4*>(h1 + (size_t)n * D1 + col0) = o;
    }
    float cs = acc[r][0] * asv.x + acc[r][1] * asv.y + acc[r][2] * asv.z + acc[r][3] * asv.w;
    float cd = acc[r][0] * adv.x + acc[r][1] * adv.y + acc[r][2] * adv.z + acc[r][3] * adv.w;
    // reduce across the 8 ct-lanes of this head (same rt, same rows)
#pragma unroll
    for (int off = 1; off < 8; off <<= 1) {
      cs += __shfl_xor(cs, off, 64);
      cd += __shfl_xor(cd, off, 64);
    }
    if ((ct & 7) == 0 && ok) {
      asrc[n * HEADS + head] = cs;
      adst[n * HEADS + head] = cd;
    }
  }
}

// ================= CSR build =================
__global__ void zero_deg(int* __restrict__ deg)
{
  int i = blockIdx.x * blockDim.x + threadIdx.x;
  if (i < N_NODES) deg[i] = 0;
}

__global__ void count_deg(const int* __restrict__ ei, int* __restrict__ deg)
{
  int e = blockIdx.x * blockDim.x + threadIdx.x;
  if (e >= E_TOT) return;
  int d = (e < N_EDGES) ? ei[N_EDGES + e] : e - N_EDGES;
  atomicAdd(deg + d, 1);
}

// phase 1: per-block (1024-node tile) total degree
__global__ __launch_bounds__(256) void scan_p1(const int* __restrict__ deg,
                                               int* __restrict__ blocksum)
{
  int base = blockIdx.x * SCAN_TILE + threadIdx.x * 4;
  int s = 0;
#pragma unroll
  for (int i = 0; i < 4; ++i) {
    int idx = base + i;
    if (idx < N_NODES) s += deg[idx];
  }
#pragma unroll
  for (int off = 1; off < 64; off <<= 1) s += __shfl_xor(s, off, 64);
  __shared__ int ws[4];
  if ((threadIdx.x & 63) == 0) ws[threadIdx.x >> 6] = s;
  __syncthreads();
  if (threadIdx.x == 0) blocksum[blockIdx.x] = ws[0] + ws[1] + ws[2] + ws[3];
}

// phase 2: one wave scans the 49 block sums
__global__ void scan_p2(const int* __restrict__ blocksum, int* __restrict__ blockoff,
                        int* __restrict__ row_off)
{
  int t = threadIdx.x;
  int v = (t < SCAN_NB) ? blocksum[t] : 0;
  int incl = v;
#pragma unroll
  for (int off = 1; off < 64; off <<= 1) {
    int u = __shfl_up(incl, off, 64);
    if (t >= off) incl += u;
  }
  if (t < SCAN_NB) blockoff[t] = incl - v;
  if (t == 0) row_off[N_NODES] = E_TOT;
}

// phase 3: per-block exclusive rescan + write row_off/cursor
__global__ __launch_bounds__(256) void scan_p3(const int* __restrict__ deg,
                                               const int* __restrict__ blockoff,
                                               int* __restrict__ row_off,
                                               int* __restrict__ cursor)
{
  const int t = threadIdx.x;
  const int lane = t & 63, wid = t >> 6;
  int base = blockIdx.x * SCAN_TILE + t * 4;
  int local[4]; int lsum = 0;
#pragma unroll
  for (int i = 0; i < 4; ++i) {
    int idx = base + i;
    local[i] = (idx < N_NODES) ? deg[idx] : 0;
    lsum += local[i];
  }
  int incl = lsum;
#pragma unroll
  for (int off = 1; off < 64; off <<= 1) {
    int u = __shfl_up(incl, off, 64);
    if (lane >= off) incl += u;
  }
  __shared__ int wtot[4];
  if (lane == 63) wtot[wid] = incl;
  __syncthreads();
  int wpre = 0;
  for (int w = 0; w < wid; ++w) wpre += wtot[w];
  int run = blockoff[blockIdx.x] + wpre + (incl - lsum);
#pragma unroll
  for (int i = 0; i < 4; ++i) {
    int idx = base + i;
    if (idx < N_NODES) { row_off[idx] = run; cursor[idx] = run; run += local[i]; }
  }
}

__global__ void scatter_csr(const int* __restrict__ ei, int* __restrict__ cursor,
                            int* __restrict__ csr_src)
{
  int e = blockIdx.x * blockDim.x + threadIdx.x;
  if (e >= E_TOT) return;
  int s, d;
  if (e < N_EDGES) { s = ei[e]; d = ei[N_EDGES + e]; }
  else             { s = d = e - N_EDGES; }
  int pos = atomicAdd(cursor + d, 1);
  csr_src[pos] = s;
}

// ============ agg1: per-node softmax + aggregate + bias + relu ============
__global__ __launch_bounds__(256) void agg1(
    const int* __restrict__ row_off, const int* __restrict__ csr_src,
    const float* __restrict__ asrc, const float* __restrict__ adst,
    const float* __restrict__ h1, const float* __restrict__ b1,
    float* __restrict__ z)
{
  int n = blockIdx.x * 4 + (threadIdx.x >> 6);
  if (n >= N_NODES) return;
  const int lane = threadIdx.x & 63;
  const int start = row_off[n], end = row_off[n + 1];
  const int h = lane & 3;
  const float adst_h = adst[n * HEADS + h];
  // phase 1: per-head max of asrc (leaky-relu monotone => max commutes)
  float vmax = -1e30f;
  for (int i = start + (lane >> 2); i < end; i += 16)
    vmax = fmaxf(vmax, asrc[csr_src[i] * HEADS + h]);
#pragma unroll
  for (int off = 4; off < 64; off <<= 1)
    vmax = fmaxf(vmax, __shfl_xor(vmax, off, 64));
  float v = vmax + adst_h;
  const float mle = v > 0.f ? v : NEG_SLOPE * v;
  // phase 2: per-head sum of exp
  float ssum = 0.f;
  for (int i = start + (lane >> 2); i < end; i += 16) {
    float tv = asrc[csr_src[i] * HEADS + h] + adst_h;
    float le = tv > 0.f ? tv : NEG_SLOPE * tv;
    ssum += __expf(le - mle);
  }
#pragma unroll
  for (int off = 4; off < 64; off <<= 1)
    ssum += __shfl_xor(ssum, off, 64);
  // broadcast this lane's two heads (lane -> channels lane, lane+64)
  const int hlo = lane >> 5, hhi = 2 + (lane >> 5);
  const float m_lo = __shfl(mle, hlo, 64);
  const float m_hi = __shfl(mle, hhi, 64);
  const float is_lo = 1.f / __shfl(ssum, hlo, 64);
  const float is_hi = 1.f / __shfl(ssum, hhi, 64);
  const float ad_lo = adst[n * HEADS + hlo];
  const float ad_hi = adst[n * HEADS + hhi];
  float acc0 = 0.f, acc1 = 0.f;
  for (int i = start; i < end; ++i) {
    int s = csr_src[i];
    float t0 = asrc[s * HEADS + hlo] + ad_lo;
    float t1 = asrc[s * HEADS + hhi] + ad_hi;
    t0 = t0 > 0.f ? t0 : NEG_SLOPE * t0;
    t1 = t1 > 0.f ? t1 : NEG_SLOPE * t1;
    float a0 = __expf(t0 - m_lo) * is_lo;
    float a1 = __expf(t1 - m_hi) * is_hi;
    acc0 += a0 * h1[s * D1 + lane];
    acc1 += a1 * h1[s * D1 + 64 + lane];
  }
  float r0 = acc0 + b1[lane];
  float r1 = acc1 + b1[64 + lane];
  z[n * D1 + lane]      = r0 > 0.f ? r0 : 0.f;
  z[n * D1 + 64 + lane] = r1 > 0.f ? r1 : 0.f;
}

// ================= GEMM2: h2 = z @ W2, fused alpha2 =================
__global__ __launch_bounds__(256) void gemm2(
    const float* __restrict__ z, const float* __restrict__ W2,
    const float* __restrict__ as2, const float* __restrict__ ad2,
    float* __restrict__ h2, float* __restrict__ asrc2, float* __restrict__ adst2)
{
  __shared__ float zs[32][IN_DIM];
  const int nb = blockIdx.x * 32;
  const int t  = threadIdx.x;
  for (int i = t; i < 32 * IN_DIM; i += 256) {
    int r = i >> 7, k = i & 127;
    int n = nb + r;
    zs[r][k] = (n < N_NODES) ? z[n * IN_DIM + k] : 0.f;
  }
  __syncthreads();
  const int col = t & 63;
  const int rbase = (t >> 6) * 8;
  const bool valid = col < OUT_DIM;
  const int colc = valid ? col : (OUT_DIM - 1);
  float acc[8];
#pragma unroll
  for (int r = 0; r < 8; ++r) acc[r] = 0.f;
  for (int k = 0; k < IN_DIM; ++k) {
    float w = W2[k * OUT_DIM + colc];
#pragma unroll
    for (int r = 0; r < 8; ++r) acc[r] += zs[rbase + r][k] * w;
  }
  const float a_s = valid ? as2[col] : 0.f;
  const float a_d = valid ? ad2[col] : 0.f;
#pragma unroll
  for (int r = 0; r < 8; ++r) {
    int n = nb + rbase + r;
    float cs = acc[r] * a_s, cd = acc[r] * a_d;
#pragma unroll
    for (int off = 32; off >= 1; off >>= 1) {
      cs += __shfl_xor(cs, off, 64);
      cd += __shfl_xor(cd, off, 64);
    }
    if (n < N_NODES) {
      if (valid) h2[n * OUT_DIM + col] = acc[r];
      if (col == 0) { asrc2[n] = cs; adst2[n] = cd; }
    }
  }
}

// ============ agg2: per-node softmax + aggregate + b2 -> out ============
__global__ __launch_bounds__(256) void agg2(
    const int* __restrict__ row_off, const int* __restrict__ csr_src,
    const float* __restrict__ asrc, const float* __restrict__ adst,
    const float* __restrict__ h2, const float* __restrict__ b2,
    float* __restrict__ out)
{
  int n = blockIdx.x * 4 + (threadIdx.x >> 6);
  if (n >= N_NODES) return;
  const int lane = threadIdx.x & 63;
  const int start = row_off[n], end = row_off[n + 1];
  const float adstn = adst[n];
  float vmax = -1e30f;
  for (int i = start + lane; i < end; i += 64)
    vmax = fmaxf(vmax, asrc[csr_src[i]]);
#pragma unroll
  for (int off = 1; off < 64; off <<= 1)
    vmax = fmaxf(vmax, __shfl_xor(vmax, off, 64));
  float v = vmax + adstn;
  const float mle = v > 0.f ? v : NEG_SLOPE * v;
  float ssum = 0.f;
  for (int i = start + lane; i < end; i += 64) {
    float t = asrc[csr_src[i]] + adstn;
    float le = t > 0.f ? t : NEG_SLOPE * t;
    ssum += __expf(le - mle);
  }
#pragma unroll
  for (int off = 1; off < 64; off <<= 1)
    ssum += __shfl_xor(ssum, off, 64);
  const float inv = 1.f / ssum;
  const bool valid = lane < OUT_DIM;
  float acc = 0.f;
  for (int i = start; i < end; ++i) {
    int s = csr_src[i];
    float t = asrc[s] + adstn;
    t = t > 0.f ? t : NEG_SLOPE * t;
    float a = __expf(t - mle) * inv;
    if (valid) acc += a * h2[s * OUT_DIM + lane];
  }
  if (valid) out[n * OUT_DIM + lane] = acc + b2[lane];
}

// ================= launch =================
extern "C" void kernel_launch(void* const* d_in, const int* in_sizes, int n_in,
                              void* d_out, int out_size, void* d_ws, size_t ws_size,
                              hipStream_t stream)
{
  const float* x    = (const float*)d_in[0];
  const int*   ei   = (const int*)  d_in[1];
  const float* W1   = (const float*)d_in[2];
  const float* as1  = (const float*)d_in[3];
  const float* ad1  = (const float*)d_in[4];
  const float* b1   = (const float*)d_in[5];
  const float* W2   = (const float*)d_in[6];
  const float* as2  = (const float*)d_in[7];
  const float* ad2  = (const float*)d_in[8];
  const float* b2   = (const float*)d_in[9];
  float* out = (float*)d_out;

  float* ws = (float*)d_ws;
  float* h1    = ws +  0;        // N*128
  float* z     = ws +  6400000;  // N*128 (relu(agg1+b1))
  float* h2    = ws + 12800000;  // N*40
  float* asrc1 = ws + 14800000;  // N*4
  float* adst1 = ws + 15000000;  // N*4
  float* asrc2 = ws + 15200000;  // N
  float* adst2 = ws + 15250000;  // N
  int* deg     = (int*)(ws + 15300000);  // N
  int* row_off = (int*)(ws + 15350000);  // N+1
  int* cursor  = (int*)(ws + 15410000);  // N
  int* csr_src = (int*)(ws + 15460000);  // E_TOT
  int* blocksum= (int*)(ws + 16310000);  // SCAN_NB
  int* blockoff= (int*)(ws + 16310100);  // SCAN_NB

  const int B = 256;
  // CSR build (by destination)
  zero_deg<<<(N_NODES + B - 1) / B, B, 0, stream>>>(deg);
  count_deg<<<(E_TOT + B - 1) / B, B, 0, stream>>>(ei, deg);
  scan_p1<<<SCAN_NB, B, 0, stream>>>(deg, blocksum);
  scan_p2<<<1, 64, 0, stream>>>(blocksum, blockoff, row_off);
  scan_p3<<<SCAN_NB, B, 0, stream>>>(deg, blockoff, row_off, cursor);
  scatter_csr<<<(E_TOT + B - 1) / B, B, 0, stream>>>(ei, cursor, csr_src);
  // layer 1
  gemm1<<<(N_NODES + 31) / 32, B, 0, stream>>>(x, W1, as1, ad1, h1, asrc1, adst1);
  agg1<<<(N_NODES + 3) / 4, B, 0, stream>>>(row_off, csr_src, asrc1, adst1, h1, b1, z);
  // layer 2
  gemm2<<<(N_NODES + 31) / 32, B, 0, stream>>>(z, W2, as2, ad2, h2, asrc2, adst2);
  agg2<<<(N_NODES + 3) / 4, B, 0, stream>>>(row_off, csr_src, asrc2, adst2, h2, b2, out);
}

// Round 6
// 452.097 us; speedup vs baseline: 5.0689x; 1.0185x over previous
//
#include <hip/hip_runtime.h>
#include <hip/hip_bf16.h>
#include <math.h>

#define N_NODES 50000
#define N_EDGES 800000
#define E_TOT   850000   // incl. self loops
#define IN_DIM  128
#define HID     32
#define HEADS   4
#define D1      128      // HEADS*HID
#define OUT_DIM 40
#define NEG_SLOPE 0.2f

#define SCAN_TILE 1024
#define SCAN_NB   ((N_NODES + SCAN_TILE - 1) / SCAN_TILE)   // 49

// ================= GEMM1: h1 = x @ W1, fused alpha_src/dst =================
__global__ __launch_bounds__(256) void gemm1(
    const float* __restrict__ x, const float* __restrict__ W,
    const float* __restrict__ as_v, const float* __restrict__ ad_v,
    float* __restrict__ h1, float* __restrict__ asrc, float* __restrict__ adst)
{
  __shared__ float xs[32][IN_DIM];
  const int nb = blockIdx.x * 32;
  const int t  = threadIdx.x;
  for (int i = t; i < 32 * (IN_DIM / 4); i += 256) {
    int r = i >> 5, k4 = (i & 31) * 4;
    int n = nb + r;
    float4 v = (n < N_NODES) ? *reinterpret_cast<const float4*>(x + (size_t)n * IN_DIM + k4)
                             : make_float4(0.f, 0.f, 0.f, 0.f);
    *reinterpret_cast<float4*>(&xs[r][k4]) = v;
  }
  __syncthreads();
  const int ct = t & 31, col0 = ct * 4;
  const int rt = t >> 5, rbase = rt * 4;
  float acc[4][4];
#pragma unroll
  for (int r = 0; r < 4; ++r)
#pragma unroll
    for (int c = 0; c < 4; ++c) acc[r][c] = 0.f;

  for (int k = 0; k < IN_DIM; k += 4) {
    float4 xv[4];
#pragma unroll
    for (int r = 0; r < 4; ++r)
      xv[r] = *reinterpret_cast<const float4*>(&xs[rbase + r][k]);
    float4 wv[4];
#pragma unroll
    for (int kk = 0; kk < 4; ++kk)
      wv[kk] = *reinterpret_cast<const float4*>(W + (size_t)(k + kk) * D1 + col0);
#pragma unroll
    for (int r = 0; r < 4; ++r) {
      acc[r][0] += xv[r].x * wv[0].x + xv[r].y * wv[1].x + xv[r].z * wv[2].x + xv[r].w * wv[3].x;
      acc[r][1] += xv[r].x * wv[0].y + xv[r].y * wv[1].y + xv[r].z * wv[2].y + xv[r].w * wv[3].y;
      acc[r][2] += xv[r].x * wv[0].z + xv[r].y * wv[1].z + xv[r].z * wv[2].z + xv[r].w * wv[3].z;
      acc[r][3] += xv[r].x * wv[0].w + xv[r].y * wv[1].w + xv[r].z * wv[2].w + xv[r].w * wv[3].w;
    }
  }

  const int head = col0 >> 5;
  const int cc0  = col0 & 31;
  const float4 asv = *reinterpret_cast<const float4*>(as_v + head * HID + cc0);
  const float4 adv = *reinterpret_cast<const float4*>(ad_v + head * HID + cc0);
#pragma unroll
  for (int r = 0; r < 4; ++r) {
    int n = nb + rbase + r;
    bool ok = n < N_NODES;
    if (ok) {
      float4 o = make_float4(acc[r][0], acc[r][1], acc[r][2], acc[r][3]);
      *reinterpret_cast<float4*>(h1 + (size_t)n * D1 + col0) = o;
    }
    float cs = acc[r][0] * asv.x + acc[r][1] * asv.y + acc[r][2] * asv.z + acc[r][3] * asv.w;
    float cd = acc[r][0] * adv.x + acc[r][1] * adv.y + acc[r][2] * adv.z + acc[r][3] * adv.w;
#pragma unroll
    for (int off = 1; off < 8; off <<= 1) {
      cs += __shfl_xor(cs, off, 64);
      cd += __shfl_xor(cd, off, 64);
    }
    if ((ct & 7) == 0 && ok) {
      asrc[n * HEADS + head] = cs;
      adst[n * HEADS + head] = cd;
    }
  }
}

// ================= CSR build =================
__global__ void zero_deg(int* __restrict__ deg)
{
  int i = blockIdx.x * blockDim.x + threadIdx.x;
  if (i < N_NODES) deg[i] = 0;
}

__global__ void count_deg(const int* __restrict__ ei, int* __restrict__ deg)
{
  int e = blockIdx.x * blockDim.x + threadIdx.x;
  if (e >= E_TOT) return;
  int d = (e < N_EDGES) ? ei[N_EDGES + e] : e - N_EDGES;
  atomicAdd(deg + d, 1);
}

__global__ __launch_bounds__(256) void scan_p1(const int* __restrict__ deg,
                                               int* __restrict__ blocksum)
{
  int base = blockIdx.x * SCAN_TILE + threadIdx.x * 4;
  int s = 0;
#pragma unroll
  for (int i = 0; i < 4; ++i) {
    int idx = base + i;
    if (idx < N_NODES) s += deg[idx];
  }
#pragma unroll
  for (int off = 1; off < 64; off <<= 1) s += __shfl_xor(s, off, 64);
  __shared__ int ws[4];
  if ((threadIdx.x & 63) == 0) ws[threadIdx.x >> 6] = s;
  __syncthreads();
  if (threadIdx.x == 0) blocksum[blockIdx.x] = ws[0] + ws[1] + ws[2] + ws[3];
}

__global__ void scan_p2(const int* __restrict__ blocksum, int* __restrict__ blockoff,
                        int* __restrict__ row_off)
{
  int t = threadIdx.x;
  int v = (t < SCAN_NB) ? blocksum[t] : 0;
  int incl = v;
#pragma unroll
  for (int off = 1; off < 64; off <<= 1) {
    int u = __shfl_up(incl, off, 64);
    if (t >= off) incl += u;
  }
  if (t < SCAN_NB) blockoff[t] = incl - v;
  if (t == 0) row_off[N_NODES] = E_TOT;
}

__global__ __launch_bounds__(256) void scan_p3(const int* __restrict__ deg,
                                               const int* __restrict__ blockoff,
                                               int* __restrict__ row_off,
                                               int* __restrict__ cursor)
{
  const int t = threadIdx.x;
  const int lane = t & 63, wid = t >> 6;
  int base = blockIdx.x * SCAN_TILE + t * 4;
  int local[4]; int lsum = 0;
#pragma unroll
  for (int i = 0; i < 4; ++i) {
    int idx = base + i;
    local[i] = (idx < N_NODES) ? deg[idx] : 0;
    lsum += local[i];
  }
  int incl = lsum;
#pragma unroll
  for (int off = 1; off < 64; off <<= 1) {
    int u = __shfl_up(incl, off, 64);
    if (lane >= off) incl += u;
  }
  __shared__ int wtot[4];
  if (lane == 63) wtot[wid] = incl;
  __syncthreads();
  int wpre = 0;
  for (int w = 0; w < wid; ++w) wpre += wtot[w];
  int run = blockoff[blockIdx.x] + wpre + (incl - lsum);
#pragma unroll
  for (int i = 0; i < 4; ++i) {
    int idx = base + i;
    if (idx < N_NODES) { row_off[idx] = run; cursor[idx] = run; run += local[i]; }
  }
}

__global__ void scatter_csr(const int* __restrict__ ei, int* __restrict__ cursor,
                            int* __restrict__ csr_src)
{
  int e = blockIdx.x * blockDim.x + threadIdx.x;
  if (e >= E_TOT) return;
  int s, d;
  if (e < N_EDGES) { s = ei[e]; d = ei[N_EDGES + e]; }
  else             { s = d = e - N_EDGES; }
  int pos = atomicAdd(cursor + d, 1);
  csr_src[pos] = s;
}

// ============ agg1: softmax (coef cached in lbuf) + aggregate + bias + relu ============
__global__ __launch_bounds__(256) void agg1(
    const int* __restrict__ row_off, const int* __restrict__ csr_src,
    const float* __restrict__ asrc, const float* __restrict__ adst,
    const float* __restrict__ h1, const float* __restrict__ b1,
    float* __restrict__ lbuf, float* __restrict__ z)
{
  int n = blockIdx.x * 4 + (threadIdx.x >> 6);
  if (n >= N_NODES) return;
  const int lane = threadIdx.x & 63;
  const int start = row_off[n], end = row_off[n + 1];
  const int h = lane & 3;
  const float adst_h = adst[n * HEADS + h];
  // phase 1: per-head max of asrc (leaky-relu monotone => max commutes)
  float vmax = -1e30f;
  for (int i = start + (lane >> 2); i < end; i += 16)
    vmax = fmaxf(vmax, asrc[csr_src[i] * HEADS + h]);
#pragma unroll
  for (int off = 4; off < 64; off <<= 1)
    vmax = fmaxf(vmax, __shfl_xor(vmax, off, 64));
  float v = vmax + adst_h;
  const float mle = v > 0.f ? v : NEG_SLOPE * v;
  // phase 2: sum of exp; store per-edge unnormalized coef (coalesced 16B/edge)
  float ssum = 0.f;
  for (int i = start + (lane >> 2); i < end; i += 16) {
    float tv = asrc[csr_src[i] * HEADS + h] + adst_h;
    float le = tv > 0.f ? tv : NEG_SLOPE * tv;
    float e = __expf(le - mle);
    lbuf[(size_t)i * 4 + h] = e;
    ssum += e;
  }
#pragma unroll
  for (int off = 4; off < 64; off <<= 1)
    ssum += __shfl_xor(ssum, off, 64);
  // phase 3: lane owns channels {2*lane, 2*lane+1}; head = lane>>4
  const int hh = lane >> 4;
  const float inv = 1.f / __shfl(ssum, hh, 64);
  float2 acc = make_float2(0.f, 0.f);
  for (int i = start; i < end; ++i) {
    int s = csr_src[i];
    float c = lbuf[(size_t)i * 4 + hh] * inv;   // broadcast within 16-lane group
    float2 hv = *reinterpret_cast<const float2*>(h1 + (size_t)s * D1 + 2 * lane);
    acc.x += c * hv.x;
    acc.y += c * hv.y;
  }
  float2 bb = *reinterpret_cast<const float2*>(b1 + 2 * lane);
  float r0 = acc.x + bb.x;
  float r1 = acc.y + bb.y;
  float2 o = make_float2(r0 > 0.f ? r0 : 0.f, r1 > 0.f ? r1 : 0.f);
  *reinterpret_cast<float2*>(z + (size_t)n * D1 + 2 * lane) = o;
}

// ================= GEMM2: h2 = z @ W2, fused alpha2 =================
__global__ __launch_bounds__(256) void gemm2(
    const float* __restrict__ z, const float* __restrict__ W2,
    const float* __restrict__ as2, const float* __restrict__ ad2,
    float* __restrict__ h2, float* __restrict__ asrc2, float* __restrict__ adst2)
{
  __shared__ float zs[32][IN_DIM];
  const int nb = blockIdx.x * 32;
  const int t  = threadIdx.x;
  for (int i = t; i < 32 * (IN_DIM / 4); i += 256) {
    int r = i >> 5, k4 = (i & 31) * 4;
    int n = nb + r;
    float4 v = (n < N_NODES) ? *reinterpret_cast<const float4*>(z + (size_t)n * IN_DIM + k4)
                             : make_float4(0.f, 0.f, 0.f, 0.f);
    *reinterpret_cast<float4*>(&zs[r][k4]) = v;
  }
  __syncthreads();
  const int col = t & 63;
  const int rbase = (t >> 6) * 8;
  const bool valid = col < OUT_DIM;
  const int colc = valid ? col : (OUT_DIM - 1);
  float acc[8];
#pragma unroll
  for (int r = 0; r < 8; ++r) acc[r] = 0.f;
  for (int k = 0; k < IN_DIM; ++k) {
    float w = W2[k * OUT_DIM + colc];
#pragma unroll
    for (int r = 0; r < 8; ++r) acc[r] += zs[rbase + r][k] * w;
  }
  const float a_s = valid ? as2[col] : 0.f;
  const float a_d = valid ? ad2[col] : 0.f;
#pragma unroll
  for (int r = 0; r < 8; ++r) {
    int n = nb + rbase + r;
    float cs = acc[r] * a_s, cd = acc[r] * a_d;
#pragma unroll
    for (int off = 32; off >= 1; off >>= 1) {
      cs += __shfl_xor(cs, off, 64);
      cd += __shfl_xor(cd, off, 64);
    }
    if (n < N_NODES) {
      if (valid) h2[n * OUT_DIM + col] = acc[r];
      if (col == 0) { asrc2[n] = cs; adst2[n] = cd; }
    }
  }
}

// ============ agg2: softmax (coef cached) + aggregate + b2 -> out ============
__global__ __launch_bounds__(256) void agg2(
    const int* __restrict__ row_off, const int* __restrict__ csr_src,
    const float* __restrict__ asrc, const float* __restrict__ adst,
    const float* __restrict__ h2, const float* __restrict__ b2,
    float* __restrict__ lbuf, float* __restrict__ out)
{
  int n = blockIdx.x * 4 + (threadIdx.x >> 6);
  if (n >= N_NODES) return;
  const int lane = threadIdx.x & 63;
  const int start = row_off[n], end = row_off[n + 1];
  const float adstn = adst[n];
  float vmax = -1e30f;
  for (int i = start + lane; i < end; i += 64)
    vmax = fmaxf(vmax, asrc[csr_src[i]]);
#pragma unroll
  for (int off = 1; off < 64; off <<= 1)
    vmax = fmaxf(vmax, __shfl_xor(vmax, off, 64));
  float v = vmax + adstn;
  const float mle = v > 0.f ? v : NEG_SLOPE * v;
  float ssum = 0.f;
  for (int i = start + lane; i < end; i += 64) {
    float t = asrc[csr_src[i]] + adstn;
    float le = t > 0.f ? t : NEG_SLOPE * t;
    float e = __expf(le - mle);
    lbuf[i] = e;
    ssum += e;
  }
#pragma unroll
  for (int off = 1; off < 64; off <<= 1)
    ssum += __shfl_xor(ssum, off, 64);
  const float inv = 1.f / ssum;
  const bool valid = lane < OUT_DIM;
  float acc = 0.f;
  for (int i = start; i < end; ++i) {
    int s = csr_src[i];
    float c = lbuf[i] * inv;                     // broadcast
    if (valid) acc += c * h2[(size_t)s * OUT_DIM + lane];
  }
  if (valid) out[(size_t)n * OUT_DIM + lane] = acc + b2[lane];
}

// ================= launch =================
extern "C" void kernel_launch(void* const* d_in, const int* in_sizes, int n_in,
                              void* d_out, int out_size, void* d_ws, size_t ws_size,
                              hipStream_t stream)
{
  const float* x    = (const float*)d_in[0];
  const int*   ei   = (const int*)  d_in[1];
  const float* W1   = (const float*)d_in[2];
  const float* as1  = (const float*)d_in[3];
  const float* ad1  = (const float*)d_in[4];
  const float* b1   = (const float*)d_in[5];
  const float* W2   = (const float*)d_in[6];
  const float* as2  = (const float*)d_in[7];
  const float* ad2  = (const float*)d_in[8];
  const float* b2   = (const float*)d_in[9];
  float* out = (float*)d_out;

  float* ws = (float*)d_ws;
  float* h1    = ws +  0;        // N*128
  float* z     = ws +  6400000;  // N*128 (relu(agg1+b1))
  float* h2    = ws + 12800000;  // N*40
  float* asrc1 = ws + 14800000;  // N*4
  float* adst1 = ws + 15000000;  // N*4
  float* asrc2 = ws + 15200000;  // N
  float* adst2 = ws + 15250000;  // N
  int* deg     = (int*)(ws + 15300000);  // N
  int* row_off = (int*)(ws + 15350000);  // N+1
  int* cursor  = (int*)(ws + 15410000);  // N
  int* csr_src = (int*)(ws + 15460000);  // E_TOT
  int* blocksum= (int*)(ws + 16310000);  // SCAN_NB
  int* blockoff= (int*)(ws + 16310100);  // SCAN_NB
  float* lbuf1 = ws + 16320000;  // E_TOT*4
  float* lbuf2 = lbuf1;          // aliases lbuf1 (layer 2 runs after layer 1)

  const int B = 256;
  // CSR build (by destination)
  zero_deg<<<(N_NODES + B - 1) / B, B, 0, stream>>>(deg);
  count_deg<<<(E_TOT + B - 1) / B, B, 0, stream>>>(ei, deg);
  scan_p1<<<SCAN_NB, B, 0, stream>>>(deg, blocksum);
  scan_p2<<<1, 64, 0, stream>>>(blocksum, blockoff, row_off);
  scan_p3<<<SCAN_NB, B, 0, stream>>>(deg, blockoff, row_off, cursor);
  scatter_csr<<<(E_TOT + B - 1) / B, B, 0, stream>>>(ei, cursor, csr_src);
  // layer 1
  gemm1<<<(N_NODES + 31) / 32, B, 0, stream>>>(x, W1, as1, ad1, h1, asrc1, adst1);
  agg1<<<(N_NODES + 3) / 4, B, 0, stream>>>(row_off, csr_src, asrc1, adst1, h1, b1, lbuf1, z);
  // layer 2
  gemm2<<<(N_NODES + 31) / 32, B, 0, stream>>>(z, W2, as2, ad2, h2, asrc2, adst2);
  agg2<<<(N_NODES + 3) / 4, B, 0, stream>>>(row_off, csr_src, asrc2, adst2, h2, b2, lbuf2, out);
}

// Round 7
// 366.196 us; speedup vs baseline: 6.2580x; 1.2346x over previous
//
#include <hip/hip_runtime.h>
#include <hip/hip_bf16.h>
#include <math.h>

#define N_NODES 50000
#define N_EDGES 800000
#define E_TOT   850000   // incl. self loops
#define IN_DIM  128
#define HID     32
#define HEADS   4
#define D1      128      // HEADS*HID
#define OUT_DIM 40
#define H2P     64       // padded h2 row stride
#define NEG_SLOPE 0.2f

#define SCAN_TILE 1024
#define SCAN_NB   ((N_NODES + SCAN_TILE - 1) / SCAN_TILE)   // 49
#define GEMM1_NB  ((N_NODES + 31) / 32)                     // 1563
#define CNT_NB    ((E_TOT + 255) / 256)                     // 3321

// ====== fused kernel: blocks [0,GEMM1_NB) do gemm1, rest do count_deg ======
__global__ __launch_bounds__(256) void gemm1_count(
    const float* __restrict__ x, const float* __restrict__ W,
    const float* __restrict__ as_v, const float* __restrict__ ad_v,
    float* __restrict__ h1, float* __restrict__ asrc, float* __restrict__ adst,
    const int* __restrict__ ei, int* __restrict__ deg)
{
  __shared__ float xs[32][IN_DIM];
  const int t = threadIdx.x;
  if (blockIdx.x >= GEMM1_NB) {
    // ---- count_deg part ----
    int e = (blockIdx.x - GEMM1_NB) * 256 + t;
    if (e < E_TOT) {
      int d = (e < N_EDGES) ? ei[N_EDGES + e] : e - N_EDGES;
      atomicAdd(deg + d, 1);
    }
    return;
  }
  // ---- gemm1 part ----
  const int nb = blockIdx.x * 32;
  for (int i = t; i < 32 * (IN_DIM / 4); i += 256) {
    int r = i >> 5, k4 = (i & 31) * 4;
    int n = nb + r;
    float4 v = (n < N_NODES) ? *reinterpret_cast<const float4*>(x + (size_t)n * IN_DIM + k4)
                             : make_float4(0.f, 0.f, 0.f, 0.f);
    *reinterpret_cast<float4*>(&xs[r][k4]) = v;
  }
  __syncthreads();
  const int ct = t & 31, col0 = ct * 4;
  const int rt = t >> 5, rbase = rt * 4;
  float acc[4][4];
#pragma unroll
  for (int r = 0; r < 4; ++r)
#pragma unroll
    for (int c = 0; c < 4; ++c) acc[r][c] = 0.f;

  for (int k = 0; k < IN_DIM; k += 4) {
    float4 xv[4];
#pragma unroll
    for (int r = 0; r < 4; ++r)
      xv[r] = *reinterpret_cast<const float4*>(&xs[rbase + r][k]);
    float4 wv[4];
#pragma unroll
    for (int kk = 0; kk < 4; ++kk)
      wv[kk] = *reinterpret_cast<const float4*>(W + (size_t)(k + kk) * D1 + col0);
#pragma unroll
    for (int r = 0; r < 4; ++r) {
      acc[r][0] += xv[r].x * wv[0].x + xv[r].y * wv[1].x + xv[r].z * wv[2].x + xv[r].w * wv[3].x;
      acc[r][1] += xv[r].x * wv[0].y + xv[r].y * wv[1].y + xv[r].z * wv[2].y + xv[r].w * wv[3].y;
      acc[r][2] += xv[r].x * wv[0].z + xv[r].y * wv[1].z + xv[r].z * wv[2].z + xv[r].w * wv[3].z;
      acc[r][3] += xv[r].x * wv[0].w + xv[r].y * wv[1].w + xv[r].z * wv[2].w + xv[r].w * wv[3].w;
    }
  }

  const int head = col0 >> 5;
  const int cc0  = col0 & 31;
  const float4 asv = *reinterpret_cast<const float4*>(as_v + head * HID + cc0);
  const float4 adv = *reinterpret_cast<const float4*>(ad_v + head * HID + cc0);
#pragma unroll
  for (int r = 0; r < 4; ++r) {
    int n = nb + rbase + r;
    bool ok = n < N_NODES;
    if (ok) {
      float4 o = make_float4(acc[r][0], acc[r][1], acc[r][2], acc[r][3]);
      *reinterpret_cast<float4*>(h1 + (size_t)n * D1 + col0) = o;
    }
    float cs = acc[r][0] * asv.x + acc[r][1] * asv.y + acc[r][2] * asv.z + acc[r][3] * asv.w;
    float cd = acc[r][0] * adv.x + acc[r][1] * adv.y + acc[r][2] * adv.z + acc[r][3] * adv.w;
#pragma unroll
    for (int off = 1; off < 8; off <<= 1) {
      cs += __shfl_xor(cs, off, 64);
      cd += __shfl_xor(cd, off, 64);
    }
    if ((ct & 7) == 0 && ok) {
      asrc[n * HEADS + head] = cs;
      adst[n * HEADS + head] = cd;
    }
  }
}

// ================= CSR build =================
__global__ void zero_deg(int* __restrict__ deg)
{
  int i = blockIdx.x * blockDim.x + threadIdx.x;
  if (i < N_NODES) deg[i] = 0;
}

__global__ __launch_bounds__(256) void scan_p1(const int* __restrict__ deg,
                                               int* __restrict__ blocksum)
{
  int base = blockIdx.x * SCAN_TILE + threadIdx.x * 4;
  int s = 0;
#pragma unroll
  for (int i = 0; i < 4; ++i) {
    int idx = base + i;
    if (idx < N_NODES) s += deg[idx];
  }
#pragma unroll
  for (int off = 1; off < 64; off <<= 1) s += __shfl_xor(s, off, 64);
  __shared__ int ws[4];
  if ((threadIdx.x & 63) == 0) ws[threadIdx.x >> 6] = s;
  __syncthreads();
  if (threadIdx.x == 0) blocksum[blockIdx.x] = ws[0] + ws[1] + ws[2] + ws[3];
}

__global__ void scan_p2(const int* __restrict__ blocksum, int* __restrict__ blockoff,
                        int* __restrict__ row_off)
{
  int t = threadIdx.x;
  int v = (t < SCAN_NB) ? blocksum[t] : 0;
  int incl = v;
#pragma unroll
  for (int off = 1; off < 64; off <<= 1) {
    int u = __shfl_up(incl, off, 64);
    if (t >= off) incl += u;
  }
  if (t < SCAN_NB) blockoff[t] = incl - v;
  if (t == 0) row_off[N_NODES] = E_TOT;
}

__global__ __launch_bounds__(256) void scan_p3(const int* __restrict__ deg,
                                               const int* __restrict__ blockoff,
                                               int* __restrict__ row_off,
                                               int* __restrict__ cursor)
{
  const int t = threadIdx.x;
  const int lane = t & 63, wid = t >> 6;
  int base = blockIdx.x * SCAN_TILE + t * 4;
  int local[4]; int lsum = 0;
#pragma unroll
  for (int i = 0; i < 4; ++i) {
    int idx = base + i;
    local[i] = (idx < N_NODES) ? deg[idx] : 0;
    lsum += local[i];
  }
  int incl = lsum;
#pragma unroll
  for (int off = 1; off < 64; off <<= 1) {
    int u = __shfl_up(incl, off, 64);
    if (lane >= off) incl += u;
  }
  __shared__ int wtot[4];
  if (lane == 63) wtot[wid] = incl;
  __syncthreads();
  int wpre = 0;
  for (int w = 0; w < wid; ++w) wpre += wtot[w];
  int run = blockoff[blockIdx.x] + wpre + (incl - lsum);
#pragma unroll
  for (int i = 0; i < 4; ++i) {
    int idx = base + i;
    if (idx < N_NODES) { row_off[idx] = run; cursor[idx] = run; run += local[i]; }
  }
}

__global__ void scatter_csr(const int* __restrict__ ei, int* __restrict__ cursor,
                            int* __restrict__ csr_src)
{
  int e = blockIdx.x * blockDim.x + threadIdx.x;
  if (e >= E_TOT) return;
  int s, d;
  if (e < N_EDGES) { s = ei[e]; d = ei[N_EDGES + e]; }
  else             { s = d = e - N_EDGES; }
  int pos = atomicAdd(cursor + d, 1);
  csr_src[pos] = s;
}

// ============ agg1: softmax (coef cached in lbuf) + aggregate + bias + relu ============
__global__ __launch_bounds__(256) void agg1(
    const int* __restrict__ row_off, const int* __restrict__ csr_src,
    const float* __restrict__ asrc, const float* __restrict__ adst,
    const float* __restrict__ h1, const float* __restrict__ b1,
    float* __restrict__ lbuf, float* __restrict__ z)
{
  int n = blockIdx.x * 4 + (threadIdx.x >> 6);
  if (n >= N_NODES) return;
  const int lane = threadIdx.x & 63;
  const int start = row_off[n], end = row_off[n + 1];
  const int h = lane & 3;
  const float adst_h = adst[n * HEADS + h];
  // phase 1: per-head max of asrc (leaky-relu monotone => max commutes)
  float vmax = -1e30f;
  for (int i = start + (lane >> 2); i < end; i += 16)
    vmax = fmaxf(vmax, asrc[csr_src[i] * HEADS + h]);
#pragma unroll
  for (int off = 4; off < 64; off <<= 1)
    vmax = fmaxf(vmax, __shfl_xor(vmax, off, 64));
  float v = vmax + adst_h;
  const float mle = v > 0.f ? v : NEG_SLOPE * v;
  // phase 2: sum of exp; store per-edge unnormalized coef
  float ssum = 0.f;
  for (int i = start + (lane >> 2); i < end; i += 16) {
    float tv = asrc[csr_src[i] * HEADS + h] + adst_h;
    float le = tv > 0.f ? tv : NEG_SLOPE * tv;
    float e = __expf(le - mle);
    lbuf[(size_t)i * 4 + h] = e;
    ssum += e;
  }
#pragma unroll
  for (int off = 4; off < 64; off <<= 1)
    ssum += __shfl_xor(ssum, off, 64);
  // phase 3: lane owns channels {2*lane, 2*lane+1}; head = lane>>4. Unrolled x4.
  const int hh = lane >> 4;
  const float inv = 1.f / __shfl(ssum, hh, 64);
  float2 acc = make_float2(0.f, 0.f);
  int i = start;
  for (; i + 4 <= end; i += 4) {
    int s0 = csr_src[i], s1 = csr_src[i + 1], s2 = csr_src[i + 2], s3 = csr_src[i + 3];
    float c0 = lbuf[(size_t)(i    ) * 4 + hh];
    float c1 = lbuf[(size_t)(i + 1) * 4 + hh];
    float c2 = lbuf[(size_t)(i + 2) * 4 + hh];
    float c3 = lbuf[(size_t)(i + 3) * 4 + hh];
    float2 v0 = *reinterpret_cast<const float2*>(h1 + (size_t)s0 * D1 + 2 * lane);
    float2 v1 = *reinterpret_cast<const float2*>(h1 + (size_t)s1 * D1 + 2 * lane);
    float2 v2 = *reinterpret_cast<const float2*>(h1 + (size_t)s2 * D1 + 2 * lane);
    float2 v3 = *reinterpret_cast<const float2*>(h1 + (size_t)s3 * D1 + 2 * lane);
    acc.x += c0 * v0.x + c1 * v1.x + c2 * v2.x + c3 * v3.x;
    acc.y += c0 * v0.y + c1 * v1.y + c2 * v2.y + c3 * v3.y;
  }
  for (; i < end; ++i) {
    int s = csr_src[i];
    float c = lbuf[(size_t)i * 4 + hh];
    float2 hv = *reinterpret_cast<const float2*>(h1 + (size_t)s * D1 + 2 * lane);
    acc.x += c * hv.x;
    acc.y += c * hv.y;
  }
  float2 bb = *reinterpret_cast<const float2*>(b1 + 2 * lane);
  float r0 = acc.x * inv + bb.x;
  float r1 = acc.y * inv + bb.y;
  float2 o = make_float2(r0 > 0.f ? r0 : 0.f, r1 > 0.f ? r1 : 0.f);
  *reinterpret_cast<float2*>(z + (size_t)n * D1 + 2 * lane) = o;
}

// ====== GEMM2: h2p = z @ W2 (padded rows of 64), fused alpha2 ======
__global__ __launch_bounds__(256) void gemm2(
    const float* __restrict__ z, const float* __restrict__ W2,
    const float* __restrict__ as2, const float* __restrict__ ad2,
    float* __restrict__ h2p, float* __restrict__ asrc2, float* __restrict__ adst2)
{
  __shared__ float zs[32][IN_DIM];
  const int nb = blockIdx.x * 32;
  const int t  = threadIdx.x;
  for (int i = t; i < 32 * (IN_DIM / 4); i += 256) {
    int r = i >> 5, k4 = (i & 31) * 4;
    int n = nb + r;
    float4 v = (n < N_NODES) ? *reinterpret_cast<const float4*>(z + (size_t)n * IN_DIM + k4)
                             : make_float4(0.f, 0.f, 0.f, 0.f);
    *reinterpret_cast<float4*>(&zs[r][k4]) = v;
  }
  __syncthreads();
  const int col = t & 63;
  const int rbase = (t >> 6) * 8;
  const bool valid = col < OUT_DIM;
  const int colc = valid ? col : (OUT_DIM - 1);
  float acc[8];
#pragma unroll
  for (int r = 0; r < 8; ++r) acc[r] = 0.f;
  for (int k = 0; k < IN_DIM; ++k) {
    float w = W2[k * OUT_DIM + colc];
#pragma unroll
    for (int r = 0; r < 8; ++r) acc[r] += zs[rbase + r][k] * w;
  }
  const float a_s = valid ? as2[col] : 0.f;
  const float a_d = valid ? ad2[col] : 0.f;
#pragma unroll
  for (int r = 0; r < 8; ++r) {
    int n = nb + rbase + r;
    float cs = acc[r] * a_s, cd = acc[r] * a_d;
#pragma unroll
    for (int off = 32; off >= 1; off >>= 1) {
      cs += __shfl_xor(cs, off, 64);
      cd += __shfl_xor(cd, off, 64);
    }
    if (n < N_NODES) {
      if (valid) h2p[(size_t)n * H2P + col] = acc[r];
      if (col == 0) { asrc2[n] = cs; adst2[n] = cd; }
    }
  }
}

// ============ agg2: softmax (coef cached) + aggregate + b2 -> out ============
__global__ __launch_bounds__(256) void agg2(
    const int* __restrict__ row_off, const int* __restrict__ csr_src,
    const float* __restrict__ asrc, const float* __restrict__ adst,
    const float* __restrict__ h2p, const float* __restrict__ b2,
    float* __restrict__ lbuf, float* __restrict__ out)
{
  int n = blockIdx.x * 4 + (threadIdx.x >> 6);
  if (n >= N_NODES) return;
  const int lane = threadIdx.x & 63;
  const int start = row_off[n], end = row_off[n + 1];
  const float adstn = adst[n];
  float vmax = -1e30f;
  for (int i = start + lane; i < end; i += 64)
    vmax = fmaxf(vmax, asrc[csr_src[i]]);
#pragma unroll
  for (int off = 1; off < 64; off <<= 1)
    vmax = fmaxf(vmax, __shfl_xor(vmax, off, 64));
  float v = vmax + adstn;
  const float mle = v > 0.f ? v : NEG_SLOPE * v;
  float ssum = 0.f;
  for (int i = start + lane; i < end; i += 64) {
    float t = asrc[csr_src[i]] + adstn;
    float le = t > 0.f ? t : NEG_SLOPE * t;
    float e = __expf(le - mle);
    lbuf[i] = e;
    ssum += e;
  }
#pragma unroll
  for (int off = 1; off < 64; off <<= 1)
    ssum += __shfl_xor(ssum, off, 64);
  const float inv = 1.f / ssum;
  if (lane < OUT_DIM) {
    float acc = 0.f;
    int i = start;
    for (; i + 4 <= end; i += 4) {
      int s0 = csr_src[i], s1 = csr_src[i + 1], s2 = csr_src[i + 2], s3 = csr_src[i + 3];
      float c0 = lbuf[i], c1 = lbuf[i + 1], c2 = lbuf[i + 2], c3 = lbuf[i + 3];
      acc += c0 * h2p[(size_t)s0 * H2P + lane]
           + c1 * h2p[(size_t)s1 * H2P + lane]
           + c2 * h2p[(size_t)s2 * H2P + lane]
           + c3 * h2p[(size_t)s3 * H2P + lane];
    }
    for (; i < end; ++i)
      acc += lbuf[i] * h2p[(size_t)csr_src[i] * H2P + lane];
    out[(size_t)n * OUT_DIM + lane] = acc * inv + b2[lane];
  }
}

// ================= launch =================
extern "C" void kernel_launch(void* const* d_in, const int* in_sizes, int n_in,
                              void* d_out, int out_size, void* d_ws, size_t ws_size,
                              hipStream_t stream)
{
  const float* x    = (const float*)d_in[0];
  const int*   ei   = (const int*)  d_in[1];
  const float* W1   = (const float*)d_in[2];
  const float* as1  = (const float*)d_in[3];
  const float* ad1  = (const float*)d_in[4];
  const float* b1   = (const float*)d_in[5];
  const float* W2   = (const float*)d_in[6];
  const float* as2  = (const float*)d_in[7];
  const float* ad2  = (const float*)d_in[8];
  const float* b2   = (const float*)d_in[9];
  float* out = (float*)d_out;

  float* ws = (float*)d_ws;
  float* h1    = ws +  0;        // N*128 (h2p aliases after agg1 is done)
  float* h2p   = ws +  0;        // N*64, aliases dead h1
  float* z     = ws +  6400000;  // N*128
  float* asrc1 = ws + 12800000;  // N*4
  float* adst1 = ws + 13000000;  // N*4
  float* asrc2 = ws + 13200000;  // N
  float* adst2 = ws + 13250000;  // N
  int* deg     = (int*)(ws + 13300000);  // N
  int* row_off = (int*)(ws + 13350000);  // N+1
  int* cursor  = (int*)(ws + 13410000);  // N
  int* csr_src = (int*)(ws + 13460000);  // E_TOT
  int* blocksum= (int*)(ws + 14320000);  // SCAN_NB
  int* blockoff= (int*)(ws + 14320100);  // SCAN_NB
  float* lbuf  = ws + 14400000;  // E_TOT*4 (layer1), first E_TOT reused by layer2

  const int B = 256;
  // CSR build (by destination) — count_deg fused into gemm1 launch below
  zero_deg<<<(N_NODES + B - 1) / B, B, 0, stream>>>(deg);
  gemm1_count<<<GEMM1_NB + CNT_NB, B, 0, stream>>>(x, W1, as1, ad1, h1, asrc1, adst1, ei, deg);
  scan_p1<<<SCAN_NB, B, 0, stream>>>(deg, blocksum);
  scan_p2<<<1, 64, 0, stream>>>(blocksum, blockoff, row_off);
  scan_p3<<<SCAN_NB, B, 0, stream>>>(deg, blockoff, row_off, cursor);
  scatter_csr<<<(E_TOT + B - 1) / B, B, 0, stream>>>(ei, cursor, csr_src);
  // layer 1
  agg1<<<(N_NODES + 3) / 4, B, 0, stream>>>(row_off, csr_src, asrc1, adst1, h1, b1, lbuf, z);
  // layer 2 (h2p overwrites h1 — h1 is dead after agg1)
  gemm2<<<(N_NODES + 31) / 32, B, 0, stream>>>(z, W2, as2, ad2, h2p, asrc2, adst2);
  agg2<<<(N_NODES + 3) / 4, B, 0, stream>>>(row_off, csr_src, asrc2, adst2, h2p, b2, lbuf, out);
}

// Round 8
// 350.664 us; speedup vs baseline: 6.5352x; 1.0443x over previous
//
#include <hip/hip_runtime.h>
#include <hip/hip_bf16.h>
#include <math.h>

#define N_NODES 50000
#define N_EDGES 800000
#define E_TOT   850000   // incl. self loops
#define IN_DIM  128
#define HID     32
#define HEADS   4
#define D1      128      // HEADS*HID
#define OUT_DIM 40
#define H2P     64       // padded h2 row stride
#define NEG_SLOPE 0.2f

#define SCAN_TILE 1024
#define SCAN_NB   ((N_NODES + SCAN_TILE - 1) / SCAN_TILE)   // 49
#define G1_ROWS   64
#define GEMM1_NB  ((N_NODES + G1_ROWS - 1) / G1_ROWS)       // 782
#define CNT_NB    ((E_TOT + 255) / 256)                     // 3321
#define W2T_LD    132

// ====== fused kernel: blocks [0,GEMM1_NB) do gemm1, rest do count_deg ======
// gemm1: 64 rows x 128 cols per block; 8x4 register tile per thread;
// W staged through double-buffered LDS in 8-k-row chunks (pure-LDS inner loop).
__global__ __launch_bounds__(256) void gemm1_count(
    const float* __restrict__ x, const float* __restrict__ W,
    const float* __restrict__ as_v, const float* __restrict__ ad_v,
    float* __restrict__ h1, float* __restrict__ asrc, float* __restrict__ adst,
    const int* __restrict__ ei, int* __restrict__ deg)
{
  __shared__ float xs[G1_ROWS][IN_DIM];   // 32 KB
  __shared__ float wbuf[2][8 * D1];       // 8 KB
  const int t = threadIdx.x;
  if (blockIdx.x >= GEMM1_NB) {
    // ---- count_deg part ----
    int e = (blockIdx.x - GEMM1_NB) * 256 + t;
    if (e < E_TOT) {
      int d = (e < N_EDGES) ? ei[N_EDGES + e] : e - N_EDGES;
      atomicAdd(deg + d, 1);
    }
    return;
  }
  // ---- gemm1 part ----
  const int nb = blockIdx.x * G1_ROWS;
  for (int i = t; i < G1_ROWS * (IN_DIM / 4); i += 256) {
    int r = i >> 5, k4 = (i & 31) * 4;
    int n = nb + r;
    float4 v = (n < N_NODES) ? *reinterpret_cast<const float4*>(x + (size_t)n * IN_DIM + k4)
                             : make_float4(0.f, 0.f, 0.f, 0.f);
    *reinterpret_cast<float4*>(&xs[r][k4]) = v;
  }
  // stage first W chunk (k rows 0..7, all 128 cols = 1024 floats; 256 thr x float4)
  float4 wreg = *reinterpret_cast<const float4*>(W + t * 4);
  *reinterpret_cast<float4*>(&wbuf[0][t * 4]) = wreg;
  __syncthreads();

  const int ct = t & 31, col0 = ct * 4;
  const int rt = t >> 5;                 // 8 row-groups of 8
  float acc[8][4];
#pragma unroll
  for (int r = 0; r < 8; ++r)
#pragma unroll
    for (int c = 0; c < 4; ++c) acc[r][c] = 0.f;

  const int NK8 = IN_DIM / 8;            // 16
  for (int k8 = 0; k8 < NK8; ++k8) {
    const int cur = k8 & 1;
    if (k8 + 1 < NK8)
      wreg = *reinterpret_cast<const float4*>(W + (size_t)(k8 + 1) * 8 * D1 + t * 4);
#pragma unroll
    for (int half = 0; half < 2; ++half) {
      const int kb = k8 * 8 + half * 4;
      float4 xv[8];
#pragma unroll
      for (int r = 0; r < 8; ++r)
        xv[r] = *reinterpret_cast<const float4*>(&xs[rt * 8 + r][kb]);
      float4 wv[4];
#pragma unroll
      for (int kk = 0; kk < 4; ++kk)
        wv[kk] = *reinterpret_cast<const float4*>(&wbuf[cur][(half * 4 + kk) * D1 + col0]);
#pragma unroll
      for (int r = 0; r < 8; ++r) {
        acc[r][0] += xv[r].x * wv[0].x + xv[r].y * wv[1].x + xv[r].z * wv[2].x + xv[r].w * wv[3].x;
        acc[r][1] += xv[r].x * wv[0].y + xv[r].y * wv[1].y + xv[r].z * wv[2].y + xv[r].w * wv[3].y;
        acc[r][2] += xv[r].x * wv[0].z + xv[r].y * wv[1].z + xv[r].z * wv[2].z + xv[r].w * wv[3].z;
        acc[r][3] += xv[r].x * wv[0].w + xv[r].y * wv[1].w + xv[r].z * wv[2].w + xv[r].w * wv[3].w;
      }
    }
    if (k8 + 1 < NK8)
      *reinterpret_cast<float4*>(&wbuf[cur ^ 1][t * 4]) = wreg;
    __syncthreads();
  }

  const int head = col0 >> 5;
  const int cc0  = col0 & 31;
  const float4 asv = *reinterpret_cast<const float4*>(as_v + head * HID + cc0);
  const float4 adv = *reinterpret_cast<const float4*>(ad_v + head * HID + cc0);
#pragma unroll
  for (int r = 0; r < 8; ++r) {
    int n = nb + rt * 8 + r;
    bool ok = n < N_NODES;
    if (ok) {
      float4 o = make_float4(acc[r][0], acc[r][1], acc[r][2], acc[r][3]);
      *reinterpret_cast<float4*>(h1 + (size_t)n * D1 + col0) = o;
    }
    float cs = acc[r][0] * asv.x + acc[r][1] * asv.y + acc[r][2] * asv.z + acc[r][3] * asv.w;
    float cd = acc[r][0] * adv.x + acc[r][1] * adv.y + acc[r][2] * adv.z + acc[r][3] * adv.w;
#pragma unroll
    for (int off = 1; off < 8; off <<= 1) {
      cs += __shfl_xor(cs, off, 64);
      cd += __shfl_xor(cd, off, 64);
    }
    if ((ct & 7) == 0 && ok) {
      asrc[n * HEADS + head] = cs;
      adst[n * HEADS + head] = cd;
    }
  }
}

// ================= CSR build =================
__global__ void zero_deg(int* __restrict__ deg)
{
  int i = blockIdx.x * blockDim.x + threadIdx.x;
  if (i < N_NODES) deg[i] = 0;
}

__global__ __launch_bounds__(256) void scan_p1(const int* __restrict__ deg,
                                               int* __restrict__ blocksum)
{
  int base = blockIdx.x * SCAN_TILE + threadIdx.x * 4;
  int s = 0;
#pragma unroll
  for (int i = 0; i < 4; ++i) {
    int idx = base + i;
    if (idx < N_NODES) s += deg[idx];
  }
#pragma unroll
  for (int off = 1; off < 64; off <<= 1) s += __shfl_xor(s, off, 64);
  __shared__ int ws[4];
  if ((threadIdx.x & 63) == 0) ws[threadIdx.x >> 6] = s;
  __syncthreads();
  if (threadIdx.x == 0) blocksum[blockIdx.x] = ws[0] + ws[1] + ws[2] + ws[3];
}

__global__ void scan_p2(const int* __restrict__ blocksum, int* __restrict__ blockoff,
                        int* __restrict__ row_off)
{
  int t = threadIdx.x;
  int v = (t < SCAN_NB) ? blocksum[t] : 0;
  int incl = v;
#pragma unroll
  for (int off = 1; off < 64; off <<= 1) {
    int u = __shfl_up(incl, off, 64);
    if (t >= off) incl += u;
  }
  if (t < SCAN_NB) blockoff[t] = incl - v;
  if (t == 0) row_off[N_NODES] = E_TOT;
}

__global__ __launch_bounds__(256) void scan_p3(const int* __restrict__ deg,
                                               const int* __restrict__ blockoff,
                                               int* __restrict__ row_off,
                                               int* __restrict__ cursor)
{
  const int t = threadIdx.x;
  const int lane = t & 63, wid = t >> 6;
  int base = blockIdx.x * SCAN_TILE + t * 4;
  int local[4]; int lsum = 0;
#pragma unroll
  for (int i = 0; i < 4; ++i) {
    int idx = base + i;
    local[i] = (idx < N_NODES) ? deg[idx] : 0;
    lsum += local[i];
  }
  int incl = lsum;
#pragma unroll
  for (int off = 1; off < 64; off <<= 1) {
    int u = __shfl_up(incl, off, 64);
    if (lane >= off) incl += u;
  }
  __shared__ int wtot[4];
  if (lane == 63) wtot[wid] = incl;
  __syncthreads();
  int wpre = 0;
  for (int w = 0; w < wid; ++w) wpre += wtot[w];
  int run = blockoff[blockIdx.x] + wpre + (incl - lsum);
#pragma unroll
  for (int i = 0; i < 4; ++i) {
    int idx = base + i;
    if (idx < N_NODES) { row_off[idx] = run; cursor[idx] = run; run += local[i]; }
  }
}

__global__ void scatter_csr(const int* __restrict__ ei, int* __restrict__ cursor,
                            int* __restrict__ csr_src)
{
  int e = blockIdx.x * blockDim.x + threadIdx.x;
  if (e >= E_TOT) return;
  int s, d;
  if (e < N_EDGES) { s = ei[e]; d = ei[N_EDGES + e]; }
  else             { s = d = e - N_EDGES; }
  int pos = atomicAdd(cursor + d, 1);
  csr_src[pos] = s;
}

// ============ agg1: softmax (coef cached in lbuf) + aggregate + bias + relu ============
__global__ __launch_bounds__(256) void agg1(
    const int* __restrict__ row_off, const int* __restrict__ csr_src,
    const float* __restrict__ asrc, const float* __restrict__ adst,
    const float* __restrict__ h1, const float* __restrict__ b1,
    float* __restrict__ lbuf, float* __restrict__ z)
{
  int n = blockIdx.x * 4 + (threadIdx.x >> 6);
  if (n >= N_NODES) return;
  const int lane = threadIdx.x & 63;
  const int start = row_off[n], end = row_off[n + 1];
  const int h = lane & 3;
  const float adst_h = adst[n * HEADS + h];
  float vmax = -1e30f;
  for (int i = start + (lane >> 2); i < end; i += 16)
    vmax = fmaxf(vmax, asrc[csr_src[i] * HEADS + h]);
#pragma unroll
  for (int off = 4; off < 64; off <<= 1)
    vmax = fmaxf(vmax, __shfl_xor(vmax, off, 64));
  float v = vmax + adst_h;
  const float mle = v > 0.f ? v : NEG_SLOPE * v;
  float ssum = 0.f;
  for (int i = start + (lane >> 2); i < end; i += 16) {
    float tv = asrc[csr_src[i] * HEADS + h] + adst_h;
    float le = tv > 0.f ? tv : NEG_SLOPE * tv;
    float e = __expf(le - mle);
    lbuf[(size_t)i * 4 + h] = e;
    ssum += e;
  }
#pragma unroll
  for (int off = 4; off < 64; off <<= 1)
    ssum += __shfl_xor(ssum, off, 64);
  const int hh = lane >> 4;
  const float inv = 1.f / __shfl(ssum, hh, 64);
  float2 acc = make_float2(0.f, 0.f);
  int i = start;
  for (; i + 4 <= end; i += 4) {
    int s0 = csr_src[i], s1 = csr_src[i + 1], s2 = csr_src[i + 2], s3 = csr_src[i + 3];
    float c0 = lbuf[(size_t)(i    ) * 4 + hh];
    float c1 = lbuf[(size_t)(i + 1) * 4 + hh];
    float c2 = lbuf[(size_t)(i + 2) * 4 + hh];
    float c3 = lbuf[(size_t)(i + 3) * 4 + hh];
    float2 v0 = *reinterpret_cast<const float2*>(h1 + (size_t)s0 * D1 + 2 * lane);
    float2 v1 = *reinterpret_cast<const float2*>(h1 + (size_t)s1 * D1 + 2 * lane);
    float2 v2 = *reinterpret_cast<const float2*>(h1 + (size_t)s2 * D1 + 2 * lane);
    float2 v3 = *reinterpret_cast<const float2*>(h1 + (size_t)s3 * D1 + 2 * lane);
    acc.x += c0 * v0.x + c1 * v1.x + c2 * v2.x + c3 * v3.x;
    acc.y += c0 * v0.y + c1 * v1.y + c2 * v2.y + c3 * v3.y;
  }
  for (; i < end; ++i) {
    int s = csr_src[i];
    float c = lbuf[(size_t)i * 4 + hh];
    float2 hv = *reinterpret_cast<const float2*>(h1 + (size_t)s * D1 + 2 * lane);
    acc.x += c * hv.x;
    acc.y += c * hv.y;
  }
  float2 bb = *reinterpret_cast<const float2*>(b1 + 2 * lane);
  float r0 = acc.x * inv + bb.x;
  float r1 = acc.y * inv + bb.y;
  float2 o = make_float2(r0 > 0.f ? r0 : 0.f, r1 > 0.f ? r1 : 0.f);
  *reinterpret_cast<float2*>(z + (size_t)n * D1 + 2 * lane) = o;
}

// ====== GEMM2: h2p = z @ W2 (padded rows of 64), W2 fully LDS-staged ======
__global__ __launch_bounds__(256) void gemm2(
    const float* __restrict__ z, const float* __restrict__ W2,
    const float* __restrict__ as2, const float* __restrict__ ad2,
    float* __restrict__ h2p, float* __restrict__ asrc2, float* __restrict__ adst2)
{
  __shared__ float zs[32][IN_DIM];        // 16 KB
  __shared__ float w2t[OUT_DIM][W2T_LD];  // ~20.6 KB, transposed W2
  const int nb = blockIdx.x * 32;
  const int t  = threadIdx.x;
  for (int i = t; i < 32 * (IN_DIM / 4); i += 256) {
    int r = i >> 5, k4 = (i & 31) * 4;
    int n = nb + r;
    float4 v = (n < N_NODES) ? *reinterpret_cast<const float4*>(z + (size_t)n * IN_DIM + k4)
                             : make_float4(0.f, 0.f, 0.f, 0.f);
    *reinterpret_cast<float4*>(&zs[r][k4]) = v;
  }
  for (int i = t; i < IN_DIM * OUT_DIM; i += 256) {
    int k = i / OUT_DIM, c = i - k * OUT_DIM;
    w2t[c][k] = W2[i];
  }
  __syncthreads();
  const int col = t & 63;
  const int rbase = (t >> 6) * 8;
  const bool valid = col < OUT_DIM;
  const int colc = valid ? col : (OUT_DIM - 1);
  float acc[8];
#pragma unroll
  for (int r = 0; r < 8; ++r) acc[r] = 0.f;
  for (int k = 0; k < IN_DIM; k += 4) {
    float4 wv = *reinterpret_cast<const float4*>(&w2t[colc][k]);
    float4 xv[8];
#pragma unroll
    for (int r = 0; r < 8; ++r)
      xv[r] = *reinterpret_cast<const float4*>(&zs[rbase + r][k]);
#pragma unroll
    for (int r = 0; r < 8; ++r)
      acc[r] += xv[r].x * wv.x + xv[r].y * wv.y + xv[r].z * wv.z + xv[r].w * wv.w;
  }
  const float a_s = valid ? as2[col] : 0.f;
  const float a_d = valid ? ad2[col] : 0.f;
#pragma unroll
  for (int r = 0; r < 8; ++r) {
    int n = nb + rbase + r;
    float cs = acc[r] * a_s, cd = acc[r] * a_d;
#pragma unroll
    for (int off = 32; off >= 1; off >>= 1) {
      cs += __shfl_xor(cs, off, 64);
      cd += __shfl_xor(cd, off, 64);
    }
    if (n < N_NODES) {
      if (valid) h2p[(size_t)n * H2P + col] = acc[r];
      if (col == 0) { asrc2[n] = cs; adst2[n] = cd; }
    }
  }
}

// ============ agg2: softmax (coef cached) + aggregate + b2 -> out ============
__global__ __launch_bounds__(256) void agg2(
    const int* __restrict__ row_off, const int* __restrict__ csr_src,
    const float* __restrict__ asrc, const float* __restrict__ adst,
    const float* __restrict__ h2p, const float* __restrict__ b2,
    float* __restrict__ lbuf, float* __restrict__ out)
{
  int n = blockIdx.x * 4 + (threadIdx.x >> 6);
  if (n >= N_NODES) return;
  const int lane = threadIdx.x & 63;
  const int start = row_off[n], end = row_off[n + 1];
  const float adstn = adst[n];
  float vmax = -1e30f;
  for (int i = start + lane; i < end; i += 64)
    vmax = fmaxf(vmax, asrc[csr_src[i]]);
#pragma unroll
  for (int off = 1; off < 64; off <<= 1)
    vmax = fmaxf(vmax, __shfl_xor(vmax, off, 64));
  float v = vmax + adstn;
  const float mle = v > 0.f ? v : NEG_SLOPE * v;
  float ssum = 0.f;
  for (int i = start + lane; i < end; i += 64) {
    float t = asrc[csr_src[i]] + adstn;
    float le = t > 0.f ? t : NEG_SLOPE * t;
    float e = __expf(le - mle);
    lbuf[i] = e;
    ssum += e;
  }
#pragma unroll
  for (int off = 1; off < 64; off <<= 1)
    ssum += __shfl_xor(ssum, off, 64);
  const float inv = 1.f / ssum;
  if (lane < OUT_DIM) {
    float acc = 0.f;
    int i = start;
    for (; i + 4 <= end; i += 4) {
      int s0 = csr_src[i], s1 = csr_src[i + 1], s2 = csr_src[i + 2], s3 = csr_src[i + 3];
      float c0 = lbuf[i], c1 = lbuf[i + 1], c2 = lbuf[i + 2], c3 = lbuf[i + 3];
      acc += c0 * h2p[(size_t)s0 * H2P + lane]
           + c1 * h2p[(size_t)s1 * H2P + lane]
           + c2 * h2p[(size_t)s2 * H2P + lane]
           + c3 * h2p[(size_t)s3 * H2P + lane];
    }
    for (; i < end; ++i)
      acc += lbuf[i] * h2p[(size_t)csr_src[i] * H2P + lane];
    out[(size_t)n * OUT_DIM + lane] = acc * inv + b2[lane];
  }
}

// ================= launch =================
extern "C" void kernel_launch(void* const* d_in, const int* in_sizes, int n_in,
                              void* d_out, int out_size, void* d_ws, size_t ws_size,
                              hipStream_t stream)
{
  const float* x    = (const float*)d_in[0];
  const int*   ei   = (const int*)  d_in[1];
  const float* W1   = (const float*)d_in[2];
  const float* as1  = (const float*)d_in[3];
  const float* ad1  = (const float*)d_in[4];
  const float* b1   = (const float*)d_in[5];
  const float* W2   = (const float*)d_in[6];
  const float* as2  = (const float*)d_in[7];
  const float* ad2  = (const float*)d_in[8];
  const float* b2   = (const float*)d_in[9];
  float* out = (float*)d_out;

  float* ws = (float*)d_ws;
  float* h1    = ws +  0;        // N*128 (h2p aliases after agg1 is done)
  float* h2p   = ws +  0;        // N*64, aliases dead h1
  float* z     = ws +  6400000;  // N*128
  float* asrc1 = ws + 12800000;  // N*4
  float* adst1 = ws + 13000000;  // N*4
  float* asrc2 = ws + 13200000;  // N
  float* adst2 = ws + 13250000;  // N
  int* deg     = (int*)(ws + 13300000);  // N
  int* row_off = (int*)(ws + 13350000);  // N+1
  int* cursor  = (int*)(ws + 13410000);  // N
  int* csr_src = (int*)(ws + 13460000);  // E_TOT
  int* blocksum= (int*)(ws + 14320000);  // SCAN_NB
  int* blockoff= (int*)(ws + 14320100);  // SCAN_NB
  float* lbuf  = ws + 14400000;  // E_TOT*4 (layer1), first E_TOT reused by layer2

  const int B = 256;
  // CSR build (by destination) — count_deg fused into gemm1 launch below
  zero_deg<<<(N_NODES + B - 1) / B, B, 0, stream>>>(deg);
  gemm1_count<<<GEMM1_NB + CNT_NB, B, 0, stream>>>(x, W1, as1, ad1, h1, asrc1, adst1, ei, deg);
  scan_p1<<<SCAN_NB, B, 0, stream>>>(deg, blocksum);
  scan_p2<<<1, 64, 0, stream>>>(blocksum, blockoff, row_off);
  scan_p3<<<SCAN_NB, B, 0, stream>>>(deg, blockoff, row_off, cursor);
  scatter_csr<<<(E_TOT + B - 1) / B, B, 0, stream>>>(ei, cursor, csr_src);
  // layer 1
  agg1<<<(N_NODES + 3) / 4, B, 0, stream>>>(row_off, csr_src, asrc1, adst1, h1, b1, lbuf, z);
  // layer 2 (h2p overwrites h1 — h1 is dead after agg1)
  gemm2<<<(N_NODES + 31) / 32, B, 0, stream>>>(z, W2, as2, ad2, h2p, asrc2, adst2);
  agg2<<<(N_NODES + 3) / 4, B, 0, stream>>>(row_off, csr_src, asrc2, adst2, h2p, b2, lbuf, out);
}

// Round 9
// 329.811 us; speedup vs baseline: 6.9484x; 1.0632x over previous
//
#include <hip/hip_runtime.h>
#include <hip/hip_bf16.h>
#include <hip/hip_fp16.h>
#include <math.h>

#define N_NODES 50000
#define N_EDGES 800000
#define E_TOT   850000   // incl. self loops
#define IN_DIM  128
#define HID     32
#define HEADS   4
#define D1      128      // HEADS*HID
#define OUT_DIM 40
#define H2P     64       // padded h2 row stride (fp16 -> 128B line per row)
#define NEG_SLOPE 0.2f

#define SCAN_TILE 1024
#define SCAN_NB   ((N_NODES + SCAN_TILE - 1) / SCAN_TILE)   // 49
#define G1_ROWS   64
#define GEMM1_NB  ((N_NODES + G1_ROWS - 1) / G1_ROWS)       // 782
#define CNT_NB    ((E_TOT + 255) / 256)                     // 3321
#define W2T_LD    132

// ====== fused kernel: blocks [0,GEMM1_NB) do gemm1, rest do count_deg ======
// gemm1: 64 rows x 128 cols per block; 8x4 register tile per thread;
// W staged through double-buffered LDS; h1 stored as fp16 for the gather.
__global__ __launch_bounds__(256) void gemm1_count(
    const float* __restrict__ x, const float* __restrict__ W,
    const float* __restrict__ as_v, const float* __restrict__ ad_v,
    __half* __restrict__ h1h, float* __restrict__ asrc, float* __restrict__ adst,
    const int* __restrict__ ei, int* __restrict__ deg)
{
  __shared__ float xs[G1_ROWS][IN_DIM];   // 32 KB
  __shared__ float wbuf[2][8 * D1];       // 8 KB
  const int t = threadIdx.x;
  if (blockIdx.x >= GEMM1_NB) {
    int e = (blockIdx.x - GEMM1_NB) * 256 + t;
    if (e < E_TOT) {
      int d = (e < N_EDGES) ? ei[N_EDGES + e] : e - N_EDGES;
      atomicAdd(deg + d, 1);
    }
    return;
  }
  const int nb = blockIdx.x * G1_ROWS;
  for (int i = t; i < G1_ROWS * (IN_DIM / 4); i += 256) {
    int r = i >> 5, k4 = (i & 31) * 4;
    int n = nb + r;
    float4 v = (n < N_NODES) ? *reinterpret_cast<const float4*>(x + (size_t)n * IN_DIM + k4)
                             : make_float4(0.f, 0.f, 0.f, 0.f);
    *reinterpret_cast<float4*>(&xs[r][k4]) = v;
  }
  float4 wreg = *reinterpret_cast<const float4*>(W + t * 4);
  *reinterpret_cast<float4*>(&wbuf[0][t * 4]) = wreg;
  __syncthreads();

  const int ct = t & 31, col0 = ct * 4;
  const int rt = t >> 5;
  float acc[8][4];
#pragma unroll
  for (int r = 0; r < 8; ++r)
#pragma unroll
    for (int c = 0; c < 4; ++c) acc[r][c] = 0.f;

  const int NK8 = IN_DIM / 8;            // 16
  for (int k8 = 0; k8 < NK8; ++k8) {
    const int cur = k8 & 1;
    if (k8 + 1 < NK8)
      wreg = *reinterpret_cast<const float4*>(W + (size_t)(k8 + 1) * 8 * D1 + t * 4);
#pragma unroll
    for (int half = 0; half < 2; ++half) {
      const int kb = k8 * 8 + half * 4;
      float4 xv[8];
#pragma unroll
      for (int r = 0; r < 8; ++r)
        xv[r] = *reinterpret_cast<const float4*>(&xs[rt * 8 + r][kb]);
      float4 wv[4];
#pragma unroll
      for (int kk = 0; kk < 4; ++kk)
        wv[kk] = *reinterpret_cast<const float4*>(&wbuf[cur][(half * 4 + kk) * D1 + col0]);
#pragma unroll
      for (int r = 0; r < 8; ++r) {
        acc[r][0] += xv[r].x * wv[0].x + xv[r].y * wv[1].x + xv[r].z * wv[2].x + xv[r].w * wv[3].x;
        acc[r][1] += xv[r].x * wv[0].y + xv[r].y * wv[1].y + xv[r].z * wv[2].y + xv[r].w * wv[3].y;
        acc[r][2] += xv[r].x * wv[0].z + xv[r].y * wv[1].z + xv[r].z * wv[2].z + xv[r].w * wv[3].z;
        acc[r][3] += xv[r].x * wv[0].w + xv[r].y * wv[1].w + xv[r].z * wv[2].w + xv[r].w * wv[3].w;
      }
    }
    if (k8 + 1 < NK8)
      *reinterpret_cast<float4*>(&wbuf[cur ^ 1][t * 4]) = wreg;
    __syncthreads();
  }

  const int head = col0 >> 5;
  const int cc0  = col0 & 31;
  const float4 asv = *reinterpret_cast<const float4*>(as_v + head * HID + cc0);
  const float4 adv = *reinterpret_cast<const float4*>(ad_v + head * HID + cc0);
#pragma unroll
  for (int r = 0; r < 8; ++r) {
    int n = nb + rt * 8 + r;
    bool ok = n < N_NODES;
    if (ok) {
      __half2 p0 = __floats2half2_rn(acc[r][0], acc[r][1]);
      __half2 p1 = __floats2half2_rn(acc[r][2], acc[r][3]);
      uint2 pk;
      pk.x = *reinterpret_cast<unsigned*>(&p0);
      pk.y = *reinterpret_cast<unsigned*>(&p1);
      *reinterpret_cast<uint2*>(h1h + (size_t)n * D1 + col0) = pk;
    }
    float cs = acc[r][0] * asv.x + acc[r][1] * asv.y + acc[r][2] * asv.z + acc[r][3] * asv.w;
    float cd = acc[r][0] * adv.x + acc[r][1] * adv.y + acc[r][2] * adv.z + acc[r][3] * adv.w;
#pragma unroll
    for (int off = 1; off < 8; off <<= 1) {
      cs += __shfl_xor(cs, off, 64);
      cd += __shfl_xor(cd, off, 64);
    }
    if ((ct & 7) == 0 && ok) {
      asrc[n * HEADS + head] = cs;
      adst[n * HEADS + head] = cd;
    }
  }
}

// ================= CSR build =================
__global__ void zero_deg(int* __restrict__ deg)
{
  int i = blockIdx.x * blockDim.x + threadIdx.x;
  if (i < N_NODES) deg[i] = 0;
}

__global__ __launch_bounds__(256) void scan_p1(const int* __restrict__ deg,
                                               int* __restrict__ blocksum)
{
  int base = blockIdx.x * SCAN_TILE + threadIdx.x * 4;
  int s = 0;
#pragma unroll
  for (int i = 0; i < 4; ++i) {
    int idx = base + i;
    if (idx < N_NODES) s += deg[idx];
  }
#pragma unroll
  for (int off = 1; off < 64; off <<= 1) s += __shfl_xor(s, off, 64);
  __shared__ int ws[4];
  if ((threadIdx.x & 63) == 0) ws[threadIdx.x >> 6] = s;
  __syncthreads();
  if (threadIdx.x == 0) blocksum[blockIdx.x] = ws[0] + ws[1] + ws[2] + ws[3];
}

__global__ void scan_p2(const int* __restrict__ blocksum, int* __restrict__ blockoff,
                        int* __restrict__ row_off)
{
  int t = threadIdx.x;
  int v = (t < SCAN_NB) ? blocksum[t] : 0;
  int incl = v;
#pragma unroll
  for (int off = 1; off < 64; off <<= 1) {
    int u = __shfl_up(incl, off, 64);
    if (t >= off) incl += u;
  }
  if (t < SCAN_NB) blockoff[t] = incl - v;
  if (t == 0) row_off[N_NODES] = E_TOT;
}

__global__ __launch_bounds__(256) void scan_p3(const int* __restrict__ deg,
                                               const int* __restrict__ blockoff,
                                               int* __restrict__ row_off,
                                               int* __restrict__ cursor)
{
  const int t = threadIdx.x;
  const int lane = t & 63, wid = t >> 6;
  int base = blockIdx.x * SCAN_TILE + t * 4;
  int local[4]; int lsum = 0;
#pragma unroll
  for (int i = 0; i < 4; ++i) {
    int idx = base + i;
    local[i] = (idx < N_NODES) ? deg[idx] : 0;
    lsum += local[i];
  }
  int incl = lsum;
#pragma unroll
  for (int off = 1; off < 64; off <<= 1) {
    int u = __shfl_up(incl, off, 64);
    if (lane >= off) incl += u;
  }
  __shared__ int wtot[4];
  if (lane == 63) wtot[wid] = incl;
  __syncthreads();
  int wpre = 0;
  for (int w = 0; w < wid; ++w) wpre += wtot[w];
  int run = blockoff[blockIdx.x] + wpre + (incl - lsum);
#pragma unroll
  for (int i = 0; i < 4; ++i) {
    int idx = base + i;
    if (idx < N_NODES) { row_off[idx] = run; cursor[idx] = run; run += local[i]; }
  }
}

__global__ void scatter_csr(const int* __restrict__ ei, int* __restrict__ cursor,
                            int* __restrict__ csr_src)
{
  int e = blockIdx.x * blockDim.x + threadIdx.x;
  if (e >= E_TOT) return;
  int s, d;
  if (e < N_EDGES) { s = ei[e]; d = ei[N_EDGES + e]; }
  else             { s = d = e - N_EDGES; }
  int pos = atomicAdd(cursor + d, 1);
  csr_src[pos] = s;
}

// ============ agg1: softmax (coef cached in lbuf) + fp16 gather + bias + relu ============
__global__ __launch_bounds__(256) void agg1(
    const int* __restrict__ row_off, const int* __restrict__ csr_src,
    const float* __restrict__ asrc, const float* __restrict__ adst,
    const __half* __restrict__ h1h, const float* __restrict__ b1,
    float* __restrict__ lbuf, float* __restrict__ z)
{
  int n = blockIdx.x * 4 + (threadIdx.x >> 6);
  if (n >= N_NODES) return;
  const int lane = threadIdx.x & 63;
  const int start = row_off[n], end = row_off[n + 1];
  const int h = lane & 3;
  const float adst_h = adst[n * HEADS + h];
  float vmax = -1e30f;
  for (int i = start + (lane >> 2); i < end; i += 16)
    vmax = fmaxf(vmax, asrc[csr_src[i] * HEADS + h]);
#pragma unroll
  for (int off = 4; off < 64; off <<= 1)
    vmax = fmaxf(vmax, __shfl_xor(vmax, off, 64));
  float v = vmax + adst_h;
  const float mle = v > 0.f ? v : NEG_SLOPE * v;
  float ssum = 0.f;
  for (int i = start + (lane >> 2); i < end; i += 16) {
    float tv = asrc[csr_src[i] * HEADS + h] + adst_h;
    float le = tv > 0.f ? tv : NEG_SLOPE * tv;
    float e = __expf(le - mle);
    lbuf[(size_t)i * 4 + h] = e;
    ssum += e;
  }
#pragma unroll
  for (int off = 4; off < 64; off <<= 1)
    ssum += __shfl_xor(ssum, off, 64);
  const int hh = lane >> 4;
  const float inv = 1.f / __shfl(ssum, hh, 64);
  float2 acc = make_float2(0.f, 0.f);
  int i = start;
  for (; i + 8 <= end; i += 8) {
    float cc[8]; float2 vv[8];
#pragma unroll
    for (int u = 0; u < 8; ++u) {
      int s = csr_src[i + u];
      cc[u] = lbuf[(size_t)(i + u) * 4 + hh];
      vv[u] = __half22float2(*(reinterpret_cast<const __half2*>(h1h + (size_t)s * D1) + lane));
    }
#pragma unroll
    for (int u = 0; u < 8; ++u) {
      acc.x += cc[u] * vv[u].x;
      acc.y += cc[u] * vv[u].y;
    }
  }
  for (; i < end; ++i) {
    int s = csr_src[i];
    float c = lbuf[(size_t)i * 4 + hh];
    float2 hv = __half22float2(*(reinterpret_cast<const __half2*>(h1h + (size_t)s * D1) + lane));
    acc.x += c * hv.x;
    acc.y += c * hv.y;
  }
  float2 bb = *reinterpret_cast<const float2*>(b1 + 2 * lane);
  float r0 = acc.x * inv + bb.x;
  float r1 = acc.y * inv + bb.y;
  float2 o = make_float2(r0 > 0.f ? r0 : 0.f, r1 > 0.f ? r1 : 0.f);
  *reinterpret_cast<float2*>(z + (size_t)n * D1 + 2 * lane) = o;
}

// ====== GEMM2: h2h = z @ W2 (fp16, padded rows of 64), W2 fully LDS-staged ======
__global__ __launch_bounds__(256) void gemm2(
    const float* __restrict__ z, const float* __restrict__ W2,
    const float* __restrict__ as2, const float* __restrict__ ad2,
    __half* __restrict__ h2h, float* __restrict__ asrc2, float* __restrict__ adst2)
{
  __shared__ float zs[32][IN_DIM];        // 16 KB
  __shared__ float w2t[OUT_DIM][W2T_LD];  // ~20.6 KB, transposed W2
  const int nb = blockIdx.x * 32;
  const int t  = threadIdx.x;
  for (int i = t; i < 32 * (IN_DIM / 4); i += 256) {
    int r = i >> 5, k4 = (i & 31) * 4;
    int n = nb + r;
    float4 v = (n < N_NODES) ? *reinterpret_cast<const float4*>(z + (size_t)n * IN_DIM + k4)
                             : make_float4(0.f, 0.f, 0.f, 0.f);
    *reinterpret_cast<float4*>(&zs[r][k4]) = v;
  }
  for (int i = t; i < IN_DIM * OUT_DIM; i += 256) {
    int k = i / OUT_DIM, c = i - k * OUT_DIM;
    w2t[c][k] = W2[i];
  }
  __syncthreads();
  const int col = t & 63;
  const int rbase = (t >> 6) * 8;
  const bool valid = col < OUT_DIM;
  const int colc = valid ? col : (OUT_DIM - 1);
  float acc[8];
#pragma unroll
  for (int r = 0; r < 8; ++r) acc[r] = 0.f;
  for (int k = 0; k < IN_DIM; k += 4) {
    float4 wv = *reinterpret_cast<const float4*>(&w2t[colc][k]);
    float4 xv[8];
#pragma unroll
    for (int r = 0; r < 8; ++r)
      xv[r] = *reinterpret_cast<const float4*>(&zs[rbase + r][k]);
#pragma unroll
    for (int r = 0; r < 8; ++r)
      acc[r] += xv[r].x * wv.x + xv[r].y * wv.y + xv[r].z * wv.z + xv[r].w * wv.w;
  }
  const float a_s = valid ? as2[col] : 0.f;
  const float a_d = valid ? ad2[col] : 0.f;
#pragma unroll
  for (int r = 0; r < 8; ++r) {
    int n = nb + rbase + r;
    float cs = acc[r] * a_s, cd = acc[r] * a_d;
#pragma unroll
    for (int off = 32; off >= 1; off >>= 1) {
      cs += __shfl_xor(cs, off, 64);
      cd += __shfl_xor(cd, off, 64);
    }
    if (n < N_NODES) {
      if (valid) h2h[(size_t)n * H2P + col] = __float2half_rn(acc[r]);
      if (col == 0) { asrc2[n] = cs; adst2[n] = cd; }
    }
  }
}

// ============ agg2: softmax (coef cached) + fp16 gather + b2 -> out ============
__global__ __launch_bounds__(256) void agg2(
    const int* __restrict__ row_off, const int* __restrict__ csr_src,
    const float* __restrict__ asrc, const float* __restrict__ adst,
    const __half* __restrict__ h2h, const float* __restrict__ b2,
    float* __restrict__ lbuf, float* __restrict__ out)
{
  int n = blockIdx.x * 4 + (threadIdx.x >> 6);
  if (n >= N_NODES) return;
  const int lane = threadIdx.x & 63;
  const int start = row_off[n], end = row_off[n + 1];
  const float adstn = adst[n];
  float vmax = -1e30f;
  for (int i = start + lane; i < end; i += 64)
    vmax = fmaxf(vmax, asrc[csr_src[i]]);
#pragma unroll
  for (int off = 1; off < 64; off <<= 1)
    vmax = fmaxf(vmax, __shfl_xor(vmax, off, 64));
  float v = vmax + adstn;
  const float mle = v > 0.f ? v : NEG_SLOPE * v;
  float ssum = 0.f;
  for (int i = start + lane; i < end; i += 64) {
    float t = asrc[csr_src[i]] + adstn;
    float le = t > 0.f ? t : NEG_SLOPE * t;
    float e = __expf(le - mle);
    lbuf[i] = e;
    ssum += e;
  }
#pragma unroll
  for (int off = 1; off < 64; off <<= 1)
    ssum += __shfl_xor(ssum, off, 64);
  const float inv = 1.f / ssum;
  if (lane < OUT_DIM) {
    float acc = 0.f;
    int i = start;
    for (; i + 8 <= end; i += 8) {
      float cc[8]; float vv[8];
#pragma unroll
      for (int u = 0; u < 8; ++u) {
        cc[u] = lbuf[i + u];
        vv[u] = __half2float(h2h[(size_t)csr_src[i + u] * H2P + lane]);
      }
#pragma unroll
      for (int u = 0; u < 8; ++u) acc += cc[u] * vv[u];
    }
    for (; i < end; ++i)
      acc += lbuf[i] * __half2float(h2h[(size_t)csr_src[i] * H2P + lane]);
    out[(size_t)n * OUT_DIM + lane] = acc * inv + b2[lane];
  }
}

// ================= launch =================
extern "C" void kernel_launch(void* const* d_in, const int* in_sizes, int n_in,
                              void* d_out, int out_size, void* d_ws, size_t ws_size,
                              hipStream_t stream)
{
  const float* x    = (const float*)d_in[0];
  const int*   ei   = (const int*)  d_in[1];
  const float* W1   = (const float*)d_in[2];
  const float* as1  = (const float*)d_in[3];
  const float* ad1  = (const float*)d_in[4];
  const float* b1   = (const float*)d_in[5];
  const float* W2   = (const float*)d_in[6];
  const float* as2  = (const float*)d_in[7];
  const float* ad2  = (const float*)d_in[8];
  const float* b2   = (const float*)d_in[9];
  float* out = (float*)d_out;

  float* ws = (float*)d_ws;
  __half* h1h  = (__half*)(ws + 0);      // N*128 halves (3.2M floats); h2h aliases
  __half* h2h  = (__half*)(ws + 0);      // N*64 halves, aliases dead h1h
  float* z     = ws +  6400000;  // N*128
  float* asrc1 = ws + 12800000;  // N*4
  float* adst1 = ws + 13000000;  // N*4
  float* asrc2 = ws + 13200000;  // N
  float* adst2 = ws + 13250000;  // N
  int* deg     = (int*)(ws + 13300000);  // N
  int* row_off = (int*)(ws + 13350000);  // N+1
  int* cursor  = (int*)(ws + 13410000);  // N
  int* csr_src = (int*)(ws + 13460000);  // E_TOT
  int* blocksum= (int*)(ws + 14320000);  // SCAN_NB
  int* blockoff= (int*)(ws + 14320100);  // SCAN_NB
  float* lbuf  = ws + 14400000;  // E_TOT*4 (layer1), first E_TOT reused by layer2

  const int B = 256;
  // CSR build (by destination) — count_deg fused into gemm1 launch below
  zero_deg<<<(N_NODES + B - 1) / B, B, 0, stream>>>(deg);
  gemm1_count<<<GEMM1_NB + CNT_NB, B, 0, stream>>>(x, W1, as1, ad1, h1h, asrc1, adst1, ei, deg);
  scan_p1<<<SCAN_NB, B, 0, stream>>>(deg, blocksum);
  scan_p2<<<1, 64, 0, stream>>>(blocksum, blockoff, row_off);
  scan_p3<<<SCAN_NB, B, 0, stream>>>(deg, blockoff, row_off, cursor);
  scatter_csr<<<(E_TOT + B - 1) / B, B, 0, stream>>>(ei, cursor, csr_src);
  // layer 1
  agg1<<<(N_NODES + 3) / 4, B, 0, stream>>>(row_off, csr_src, asrc1, adst1, h1h, b1, lbuf, z);
  // layer 2 (h2h overwrites h1h — h1h is dead after agg1)
  gemm2<<<(N_NODES + 31) / 32, B, 0, stream>>>(z, W2, as2, ad2, h2h, asrc2, adst2);
  agg2<<<(N_NODES + 3) / 4, B, 0, stream>>>(row_off, csr_src, asrc2, adst2, h2h, b2, lbuf, out);
}

// Round 12
// 319.214 us; speedup vs baseline: 7.1791x; 1.0332x over previous
//
#include <hip/hip_runtime.h>
#include <hip/hip_bf16.h>
#include <hip/hip_fp16.h>
#include <math.h>

#define N_NODES 50000
#define N_EDGES 800000
#define E_TOT   850000   // incl. self loops
#define IN_DIM  128
#define HID     32
#define HEADS   4
#define D1      128      // HEADS*HID
#define OUT_DIM 40
#define H2P     64       // padded h2 row stride (fp16 -> 128B line per row)
#define NEG_SLOPE 0.2f
#define CAP     96       // max cached edges per node in LDS (deg max ~40)

#define SCAN_TILE 1024
#define SCAN_NB   ((N_NODES + SCAN_TILE - 1) / SCAN_TILE)   // 49
#define GEMM1_NB  ((N_NODES + 63) / 64)                     // 782
#define W2T_LD    132

typedef _Float16 f16x8 __attribute__((ext_vector_type(8)));
typedef float    f32x4 __attribute__((ext_vector_type(4)));

// ====== init: blocks [0,64) repack W into fp16 B-fragment order; rest zero deg ======
// wf[((kc*8+nt)*64+lane)*8+j] = W[kc*32+(lane>>4)*8+j][nt*16+(lane&15)]
__global__ __launch_bounds__(256) void init_wf_deg(
    const float* __restrict__ W, _Float16* __restrict__ wf, int* __restrict__ deg)
{
  const int b = blockIdx.x, t = threadIdx.x;
  if (b < 64) {
    int tid = b * 256 + t;
    int j = tid & 7, lane = (tid >> 3) & 63, nt = (tid >> 9) & 7, kc = tid >> 12;
    int k = kc * 32 + ((lane >> 4) << 3) + j;
    int n = nt * 16 + (lane & 15);
    wf[tid] = (_Float16)W[k * D1 + n];
  } else {
    int i = (b - 64) * 256 + t;
    if (i < N_NODES) deg[i] = 0;
  }
}

// ====== gemm1 via MFMA (fp16 in, fp32 acc), LDS-free; count_deg fused as tail ======
__global__ __launch_bounds__(256) void gemm1_mfma_count(
    const float* __restrict__ x, const _Float16* __restrict__ wf,
    const float* __restrict__ as_v, const float* __restrict__ ad_v,
    _Float16* __restrict__ h1h, float* __restrict__ asrc, float* __restrict__ adst,
    const int* __restrict__ ei, int* __restrict__ deg)
{
  const int t = threadIdx.x;
  const int wave = t >> 6, lane = t & 63;
  const int lr = lane & 15, lq = lane >> 4;
  const int rowbase = blockIdx.x * 64 + wave * 16;
  const int arow = rowbase + lr;           // A-fragment row for this lane

  f32x4 acc[8];
#pragma unroll
  for (int nt = 0; nt < 8; ++nt) acc[nt] = (f32x4){0.f, 0.f, 0.f, 0.f};

  const float* xrow = x + (size_t)arow * IN_DIM;
  const f16x8* wfv = reinterpret_cast<const f16x8*>(wf);
#pragma unroll
  for (int kc = 0; kc < 4; ++kc) {
    float4 lo = make_float4(0.f, 0.f, 0.f, 0.f), hi = lo;
    if (arow < N_NODES) {
      lo = *reinterpret_cast<const float4*>(xrow + kc * 32 + lq * 8);
      hi = *reinterpret_cast<const float4*>(xrow + kc * 32 + lq * 8 + 4);
    }
    f16x8 a;
    a[0] = (_Float16)lo.x; a[1] = (_Float16)lo.y; a[2] = (_Float16)lo.z; a[3] = (_Float16)lo.w;
    a[4] = (_Float16)hi.x; a[5] = (_Float16)hi.y; a[6] = (_Float16)hi.z; a[7] = (_Float16)hi.w;
    const f16x8* bbase = wfv + (size_t)(kc * 8) * 64 + lane;
#pragma unroll
    for (int nt = 0; nt < 8; ++nt) {
      f16x8 bfrag = bbase[nt * 64];
      acc[nt] = __builtin_amdgcn_mfma_f32_16x16x32_f16(a, bfrag, acc[nt], 0, 0, 0);
    }
  }

  // ---- epilogue: h1 (fp16) stores + fused alpha reductions ----
  // D layout: col = lane&15 (within 16-tile), row = (lane>>4)*4 + reg  [m89-verified]
  float as_lo[4], as_hi[4], ad_lo[4], ad_hi[4];
#pragma unroll
  for (int h = 0; h < 4; ++h) {
    as_lo[h] = as_v[h * HID + lr];      ad_lo[h] = ad_v[h * HID + lr];
    as_hi[h] = as_v[h * HID + 16 + lr]; ad_hi[h] = ad_v[h * HID + 16 + lr];
  }
#pragma unroll
  for (int nt = 0; nt < 8; ++nt) {
#pragma unroll
    for (int r = 0; r < 4; ++r) {
      int m = rowbase + lq * 4 + r;
      if (m < N_NODES) h1h[(size_t)m * D1 + nt * 16 + lr] = (_Float16)acc[nt][r];
    }
  }
#pragma unroll
  for (int h = 0; h < 4; ++h) {
#pragma unroll
    for (int r = 0; r < 4; ++r) {
      float ps = acc[2 * h][r] * as_lo[h] + acc[2 * h + 1][r] * as_hi[h];
      float pd = acc[2 * h][r] * ad_lo[h] + acc[2 * h + 1][r] * ad_hi[h];
#pragma unroll
      for (int off = 1; off < 16; off <<= 1) {
        ps += __shfl_xor(ps, off, 64);
        pd += __shfl_xor(pd, off, 64);
      }
      int m = rowbase + lq * 4 + r;
      if (lr == 0 && m < N_NODES) {
        asrc[m * HEADS + h] = ps;
        adst[m * HEADS + h] = pd;
      }
    }
  }
  // ---- count_deg tail (grid-stride over edges) ----
  for (int e = blockIdx.x * 256 + t; e < E_TOT; e += gridDim.x * 256) {
    int d = (e < N_EDGES) ? ei[N_EDGES + e] : e - N_EDGES;
    atomicAdd(deg + d, 1);
  }
}

// ================= CSR build =================
__global__ __launch_bounds__(256) void scan_p1(const int* __restrict__ deg,
                                               int* __restrict__ blocksum)
{
  int base = blockIdx.x * SCAN_TILE + threadIdx.x * 4;
  int s = 0;
#pragma unroll
  for (int i = 0; i < 4; ++i) {
    int idx = base + i;
    if (idx < N_NODES) s += deg[idx];
  }
#pragma unroll
  for (int off = 1; off < 64; off <<= 1) s += __shfl_xor(s, off, 64);
  __shared__ int ws[4];
  if ((threadIdx.x & 63) == 0) ws[threadIdx.x >> 6] = s;
  __syncthreads();
  if (threadIdx.x == 0) blocksum[blockIdx.x] = ws[0] + ws[1] + ws[2] + ws[3];
}

__global__ void scan_p2(const int* __restrict__ blocksum, int* __restrict__ blockoff,
                        int* __restrict__ row_off)
{
  int t = threadIdx.x;
  int v = (t < SCAN_NB) ? blocksum[t] : 0;
  int incl = v;
#pragma unroll
  for (int off = 1; off < 64; off <<= 1) {
    int u = __shfl_up(incl, off, 64);
    if (t >= off) incl += u;
  }
  if (t < SCAN_NB) blockoff[t] = incl - v;
  if (t == 0) row_off[N_NODES] = E_TOT;
}

__global__ __launch_bounds__(256) void scan_p3(const int* __restrict__ deg,
                                               const int* __restrict__ blockoff,
                                               int* __restrict__ row_off,
                                               int* __restrict__ cursor)
{
  const int t = threadIdx.x;
  const int lane = t & 63, wid = t >> 6;
  int base = blockIdx.x * SCAN_TILE + t * 4;
  int local[4]; int lsum = 0;
#pragma unroll
  for (int i = 0; i < 4; ++i) {
    int idx = base + i;
    local[i] = (idx < N_NODES) ? deg[idx] : 0;
    lsum += local[i];
  }
  int incl = lsum;
#pragma unroll
  for (int off = 1; off < 64; off <<= 1) {
    int u = __shfl_up(incl, off, 64);
    if (lane >= off) incl += u;
  }
  __shared__ int wtot[4];
  if (lane == 63) wtot[wid] = incl;
  __syncthreads();
  int wpre = 0;
  for (int w = 0; w < wid; ++w) wpre += wtot[w];
  int run = blockoff[blockIdx.x] + wpre + (incl - lsum);
#pragma unroll
  for (int i = 0; i < 4; ++i) {
    int idx = base + i;
    if (idx < N_NODES) { row_off[idx] = run; cursor[idx] = run; run += local[i]; }
  }
}

__global__ void scatter_csr(const int* __restrict__ ei, int* __restrict__ cursor,
                            int* __restrict__ csr_src)
{
  int e = blockIdx.x * blockDim.x + threadIdx.x;
  if (e >= E_TOT) return;
  int s, d;
  if (e < N_EDGES) { s = ei[e]; d = ei[N_EDGES + e]; }
  else             { s = d = e - N_EDGES; }
  int pos = atomicAdd(cursor + d, 1);
  csr_src[pos] = s;
}

// ============ agg1: softmax (coefs in LDS) + fp16 gather + bias + relu ============
__global__ __launch_bounds__(256) void agg1(
    const int* __restrict__ row_off, const int* __restrict__ csr_src,
    const float* __restrict__ asrc, const float* __restrict__ adst,
    const __half* __restrict__ h1h, const float* __restrict__ b1,
    float* __restrict__ lbuf, float* __restrict__ z)
{
  __shared__ float cbuf[4][CAP * 4];
  const int w = threadIdx.x >> 6;
  int n = blockIdx.x * 4 + w;
  if (n >= N_NODES) return;
  const int lane = threadIdx.x & 63;
  const int start = row_off[n], end = row_off[n + 1];
  const bool useL = (end - start) <= CAP;
  float* cb = cbuf[w];
  const int h = lane & 3;
  const float adst_h = adst[n * HEADS + h];
  float vmax = -1e30f;
  for (int i = start + (lane >> 2); i < end; i += 16)
    vmax = fmaxf(vmax, asrc[csr_src[i] * HEADS + h]);
#pragma unroll
  for (int off = 4; off < 64; off <<= 1)
    vmax = fmaxf(vmax, __shfl_xor(vmax, off, 64));
  float v = vmax + adst_h;
  const float mle = v > 0.f ? v : NEG_SLOPE * v;
  float ssum = 0.f;
  for (int i = start + (lane >> 2); i < end; i += 16) {
    float tv = asrc[csr_src[i] * HEADS + h] + adst_h;
    float le = tv > 0.f ? tv : NEG_SLOPE * tv;
    float e = __expf(le - mle);
    if (useL) cb[(i - start) * 4 + h] = e;
    else      lbuf[(size_t)i * 4 + h] = e;
    ssum += e;
  }
#pragma unroll
  for (int off = 4; off < 64; off <<= 1)
    ssum += __shfl_xor(ssum, off, 64);
  const int hh = lane >> 4;
  const float inv = 1.f / __shfl(ssum, hh, 64);
  float2 acc = make_float2(0.f, 0.f);
  if (useL) {
    int i = start;
    for (; i + 8 <= end; i += 8) {
      float cc[8]; float2 vv[8];
#pragma unroll
      for (int u = 0; u < 8; ++u) {
        int s = csr_src[i + u];
        cc[u] = cb[(i + u - start) * 4 + hh];
        vv[u] = __half22float2(*(reinterpret_cast<const __half2*>(h1h + (size_t)s * D1) + lane));
      }
#pragma unroll
      for (int u = 0; u < 8; ++u) {
        acc.x += cc[u] * vv[u].x;
        acc.y += cc[u] * vv[u].y;
      }
    }
    for (; i < end; ++i) {
      int s = csr_src[i];
      float c = cb[(i - start) * 4 + hh];
      float2 hv = __half22float2(*(reinterpret_cast<const __half2*>(h1h + (size_t)s * D1) + lane));
      acc.x += c * hv.x;
      acc.y += c * hv.y;
    }
  } else {
    for (int i = start; i < end; ++i) {
      int s = csr_src[i];
      float c = lbuf[(size_t)i * 4 + hh];
      float2 hv = __half22float2(*(reinterpret_cast<const __half2*>(h1h + (size_t)s * D1) + lane));
      acc.x += c * hv.x;
      acc.y += c * hv.y;
    }
  }
  float2 bb = *reinterpret_cast<const float2*>(b1 + 2 * lane);
  float r0 = acc.x * inv + bb.x;
  float r1 = acc.y * inv + bb.y;
  float2 o = make_float2(r0 > 0.f ? r0 : 0.f, r1 > 0.f ? r1 : 0.f);
  *reinterpret_cast<float2*>(z + (size_t)n * D1 + 2 * lane) = o;
}

// ====== GEMM2: h2h = z @ W2 (fp16, padded rows of 64), W2 fully LDS-staged ======
__global__ __launch_bounds__(256) void gemm2(
    const float* __restrict__ z, const float* __restrict__ W2,
    const float* __restrict__ as2, const float* __restrict__ ad2,
    __half* __restrict__ h2h, float* __restrict__ asrc2, float* __restrict__ adst2)
{
  __shared__ float zs[32][IN_DIM];
  __shared__ float w2t[OUT_DIM][W2T_LD];
  const int nb = blockIdx.x * 32;
  const int t  = threadIdx.x;
  for (int i = t; i < 32 * (IN_DIM / 4); i += 256) {
    int r = i >> 5, k4 = (i & 31) * 4;
    int n = nb + r;
    float4 v = (n < N_NODES) ? *reinterpret_cast<const float4*>(z + (size_t)n * IN_DIM + k4)
                             : make_float4(0.f, 0.f, 0.f, 0.f);
    *reinterpret_cast<float4*>(&zs[r][k4]) = v;
  }
  for (int i = t; i < IN_DIM * OUT_DIM; i += 256) {
    int k = i / OUT_DIM, c = i - k * OUT_DIM;
    w2t[c][k] = W2[i];
  }
  __syncthreads();
  const int col = t & 63;
  const int rbase = (t >> 6) * 8;
  const bool valid = col < OUT_DIM;
  const int colc = valid ? col : (OUT_DIM - 1);
  float acc[8];
#pragma unroll
  for (int r = 0; r < 8; ++r) acc[r] = 0.f;
  for (int k = 0; k < IN_DIM; k += 4) {
    float4 wv = *reinterpret_cast<const float4*>(&w2t[colc][k]);
    float4 xv[8];
#pragma unroll
    for (int r = 0; r < 8; ++r)
      xv[r] = *reinterpret_cast<const float4*>(&zs[rbase + r][k]);
#pragma unroll
    for (int r = 0; r < 8; ++r)
      acc[r] += xv[r].x * wv.x + xv[r].y * wv.y + xv[r].z * wv.z + xv[r].w * wv.w;
  }
  const float a_s = valid ? as2[col] : 0.f;
  const float a_d = valid ? ad2[col] : 0.f;
#pragma unroll
  for (int r = 0; r < 8; ++r) {
    int n = nb + rbase + r;
    float cs = acc[r] * a_s, cd = acc[r] * a_d;
#pragma unroll
    for (int off = 32; off >= 1; off >>= 1) {
      cs += __shfl_xor(cs, off, 64);
      cd += __shfl_xor(cd, off, 64);
    }
    if (n < N_NODES) {
      if (valid) h2h[(size_t)n * H2P + col] = __float2half_rn(acc[r]);
      if (col == 0) { asrc2[n] = cs; adst2[n] = cd; }
    }
  }
}

// ============ agg2: softmax (coefs in LDS) + fp16 gather + b2 -> out ============
__global__ __launch_bounds__(256) void agg2(
    const int* __restrict__ row_off, const int* __restrict__ csr_src,
    const float* __restrict__ asrc, const float* __restrict__ adst,
    const __half* __restrict__ h2h, const float* __restrict__ b2,
    float* __restrict__ lbuf, float* __restrict__ out)
{
  __shared__ float cbuf[4][CAP];
  const int w = threadIdx.x >> 6;
  int n = blockIdx.x * 4 + w;
  if (n >= N_NODES) return;
  const int lane = threadIdx.x & 63;
  const int start = row_off[n], end = row_off[n + 1];
  const bool useL = (end - start) <= CAP;
  float* cb = cbuf[w];
  const float adstn = adst[n];
  float vmax = -1e30f;
  for (int i = start + lane; i < end; i += 64)
    vmax = fmaxf(vmax, asrc[csr_src[i]]);
#pragma unroll
  for (int off = 1; off < 64; off <<= 1)
    vmax = fmaxf(vmax, __shfl_xor(vmax, off, 64));
  float v = vmax + adstn;
  const float mle = v > 0.f ? v : NEG_SLOPE * v;
  float ssum = 0.f;
  for (int i = start + lane; i < end; i += 64) {
    float t = asrc[csr_src[i]] + adstn;
    float le = t > 0.f ? t : NEG_SLOPE * t;
    float e = __expf(le - mle);
    if (useL) cb[i - start] = e;
    else      lbuf[i] = e;
    ssum += e;
  }
#pragma unroll
  for (int off = 1; off < 64; off <<= 1)
    ssum += __shfl_xor(ssum, off, 64);
  const float inv = 1.f / ssum;
  if (lane < OUT_DIM) {
    float acc = 0.f;
    if (useL) {
      int i = start;
      for (; i + 8 <= end; i += 8) {
        float cc[8]; float vv[8];
#pragma unroll
        for (int u = 0; u < 8; ++u) {
          cc[u] = cb[i + u - start];
          vv[u] = __half2float(h2h[(size_t)csr_src[i + u] * H2P + lane]);
        }
#pragma unroll
        for (int u = 0; u < 8; ++u) acc += cc[u] * vv[u];
      }
      for (; i < end; ++i)
        acc += cb[i - start] * __half2float(h2h[(size_t)csr_src[i] * H2P + lane]);
    } else {
      for (int i = start; i < end; ++i)
        acc += lbuf[i] * __half2float(h2h[(size_t)csr_src[i] * H2P + lane]);
    }
    out[(size_t)n * OUT_DIM + lane] = acc * inv + b2[lane];
  }
}

// ================= launch =================
extern "C" void kernel_launch(void* const* d_in, const int* in_sizes, int n_in,
                              void* d_out, int out_size, void* d_ws, size_t ws_size,
                              hipStream_t stream)
{
  const float* x    = (const float*)d_in[0];
  const int*   ei   = (const int*)  d_in[1];
  const float* W1   = (const float*)d_in[2];
  const float* as1  = (const float*)d_in[3];
  const float* ad1  = (const float*)d_in[4];
  const float* b1   = (const float*)d_in[5];
  const float* W2   = (const float*)d_in[6];
  const float* as2  = (const float*)d_in[7];
  const float* ad2  = (const float*)d_in[8];
  const float* b2   = (const float*)d_in[9];
  float* out = (float*)d_out;

  float* ws = (float*)d_ws;
  _Float16* h1h = (_Float16*)(ws + 0);   // N*128 halves; h2h aliases
  __half*   h2h = (__half*)(ws + 0);     // N*64 halves, aliases dead h1h
  float* z     = ws +  6400000;  // N*128
  float* asrc1 = ws + 12800000;  // N*4
  float* adst1 = ws + 13000000;  // N*4
  float* asrc2 = ws + 13200000;  // N
  float* adst2 = ws + 13250000;  // N
  int* deg     = (int*)(ws + 13300000);  // N
  int* row_off = (int*)(ws + 13350000);  // N+1
  int* cursor  = (int*)(ws + 13410000);  // N
  int* csr_src = (int*)(ws + 13460000);  // E_TOT
  int* blocksum= (int*)(ws + 14320000);  // SCAN_NB
  int* blockoff= (int*)(ws + 14320100);  // SCAN_NB
  float* lbuf  = ws + 14400000;  // E_TOT*4 fallback coef buffer
  _Float16* wf = (_Float16*)(ws + 17800000);  // 16384 halves = 32KB

  const int B = 256;
  // W repack (fp16 B-fragments) + deg zero, one fused launch
  init_wf_deg<<<64 + (N_NODES + B - 1) / B, B, 0, stream>>>(W1, wf, deg);
  // layer-1 GEMM via MFMA + fused count_deg
  gemm1_mfma_count<<<GEMM1_NB, B, 0, stream>>>(x, wf, as1, ad1, h1h, asrc1, adst1, ei, deg);
  scan_p1<<<SCAN_NB, B, 0, stream>>>(deg, blocksum);
  scan_p2<<<1, 64, 0, stream>>>(blocksum, blockoff, row_off);
  scan_p3<<<SCAN_NB, B, 0, stream>>>(deg, blockoff, row_off, cursor);
  scatter_csr<<<(E_TOT + B - 1) / B, B, 0, stream>>>(ei, cursor, csr_src);
  // layer 1 aggregate
  agg1<<<(N_NODES + 3) / 4, B, 0, stream>>>(row_off, csr_src, asrc1, adst1,
                                            (const __half*)h1h, b1, lbuf, z);
  // layer 2 (h2h overwrites h1h — h1h is dead after agg1)
  gemm2<<<(N_NODES + 31) / 32, B, 0, stream>>>(z, W2, as2, ad2, h2h, asrc2, adst2);
  agg2<<<(N_NODES + 3) / 4, B, 0, stream>>>(row_off, csr_src, asrc2, adst2, h2h, b2, lbuf, out);
}

// Round 16
// 310.442 us; speedup vs baseline: 7.3819x; 1.0283x over previous
//
#include <hip/hip_runtime.h>
#include <hip/hip_bf16.h>
#include <hip/hip_fp16.h>
#include <math.h>

#define N_NODES 50000
#define N_EDGES 800000
#define E_TOT   850000   // incl. self loops
#define IN_DIM  128
#define HID     32
#define HEADS   4
#define D1      128      // HEADS*HID
#define OUT_DIM 40
#define H2P     64       // padded h2 row stride (fp16 -> 128B line per row)
#define NEG_SLOPE 0.2f
#define CAP     96       // max cached edges per node in LDS (deg max ~40)

#define SCAN_TILE 1024
#define SCAN_NB   ((N_NODES + SCAN_TILE - 1) / SCAN_TILE)   // 49
#define GEMM1_NB  ((N_NODES + 63) / 64)                     // 782
#define SCT_NB    ((E_TOT + 255) / 256)                     // 3321
#define W2T_LD    132

typedef _Float16 f16x8 __attribute__((ext_vector_type(8)));
typedef float    f32x4 __attribute__((ext_vector_type(4)));

// ====== init: blocks [0,64) repack W into fp16 B-fragment order; rest zero deg ======
// wf[((kc*8+nt)*64+lane)*8+j] = W[kc*32+(lane>>4)*8+j][nt*16+(lane&15)]
__global__ __launch_bounds__(256) void init_wf_deg(
    const float* __restrict__ W, _Float16* __restrict__ wf, int* __restrict__ deg)
{
  const int b = blockIdx.x, t = threadIdx.x;
  if (b < 64) {
    int tid = b * 256 + t;
    int j = tid & 7, lane = (tid >> 3) & 63, nt = (tid >> 9) & 7, kc = tid >> 12;
    int k = kc * 32 + ((lane >> 4) << 3) + j;
    int n = nt * 16 + (lane & 15);
    wf[tid] = (_Float16)W[k * D1 + n];
  } else {
    int i = (b - 64) * 256 + t;
    if (i < N_NODES) deg[i] = 0;
  }
}

__global__ void count_deg(const int* __restrict__ ei, int* __restrict__ deg)
{
  int e = blockIdx.x * blockDim.x + threadIdx.x;
  if (e >= E_TOT) return;
  int d = (e < N_EDGES) ? ei[N_EDGES + e] : e - N_EDGES;
  atomicAdd(deg + d, 1);
}

// ================= CSR scan =================
__global__ __launch_bounds__(256) void scan_p1(const int* __restrict__ deg,
                                               int* __restrict__ blocksum)
{
  int base = blockIdx.x * SCAN_TILE + threadIdx.x * 4;
  int s = 0;
#pragma unroll
  for (int i = 0; i < 4; ++i) {
    int idx = base + i;
    if (idx < N_NODES) s += deg[idx];
  }
#pragma unroll
  for (int off = 1; off < 64; off <<= 1) s += __shfl_xor(s, off, 64);
  __shared__ int ws[4];
  if ((threadIdx.x & 63) == 0) ws[threadIdx.x >> 6] = s;
  __syncthreads();
  if (threadIdx.x == 0) blocksum[blockIdx.x] = ws[0] + ws[1] + ws[2] + ws[3];
}

__global__ void scan_p2(const int* __restrict__ blocksum, int* __restrict__ blockoff,
                        int* __restrict__ row_off)
{
  int t = threadIdx.x;
  int v = (t < SCAN_NB) ? blocksum[t] : 0;
  int incl = v;
#pragma unroll
  for (int off = 1; off < 64; off <<= 1) {
    int u = __shfl_up(incl, off, 64);
    if (t >= off) incl += u;
  }
  if (t < SCAN_NB) blockoff[t] = incl - v;
  if (t == 0) row_off[N_NODES] = E_TOT;
}

__global__ __launch_bounds__(256) void scan_p3(const int* __restrict__ deg,
                                               const int* __restrict__ blockoff,
                                               int* __restrict__ row_off,
                                               int* __restrict__ cursor)
{
  const int t = threadIdx.x;
  const int lane = t & 63, wid = t >> 6;
  int base = blockIdx.x * SCAN_TILE + t * 4;
  int local[4]; int lsum = 0;
#pragma unroll
  for (int i = 0; i < 4; ++i) {
    int idx = base + i;
    local[i] = (idx < N_NODES) ? deg[idx] : 0;
    lsum += local[i];
  }
  int incl = lsum;
#pragma unroll
  for (int off = 1; off < 64; off <<= 1) {
    int u = __shfl_up(incl, off, 64);
    if (lane >= off) incl += u;
  }
  __shared__ int wtot[4];
  if (lane == 63) wtot[wid] = incl;
  __syncthreads();
  int wpre = 0;
  for (int w = 0; w < wid; ++w) wpre += wtot[w];
  int run = blockoff[blockIdx.x] + wpre + (incl - lsum);
#pragma unroll
  for (int i = 0; i < 4; ++i) {
    int idx = base + i;
    if (idx < N_NODES) { row_off[idx] = run; cursor[idx] = run; run += local[i]; }
  }
}

// ====== fused: blocks [0,GEMM1_NB) gemm1 via MFMA; rest scatter_csr (ushort) ======
__global__ __launch_bounds__(256) void gemm1_mfma_scatter(
    const float* __restrict__ x, const _Float16* __restrict__ wf,
    const float* __restrict__ as_v, const float* __restrict__ ad_v,
    _Float16* __restrict__ h1h, float* __restrict__ asrc, float* __restrict__ adst,
    const int* __restrict__ ei, int* __restrict__ cursor,
    unsigned short* __restrict__ csr_src)
{
  const int t = threadIdx.x;
  if (blockIdx.x >= GEMM1_NB) {
    // ---- scatter part ----
    int e = (blockIdx.x - GEMM1_NB) * 256 + t;
    if (e < E_TOT) {
      int s, d;
      if (e < N_EDGES) { s = ei[e]; d = ei[N_EDGES + e]; }
      else             { s = d = e - N_EDGES; }
      int pos = atomicAdd(cursor + d, 1);
      csr_src[pos] = (unsigned short)s;
    }
    return;
  }
  // ---- gemm1 MFMA part ----
  const int wave = t >> 6, lane = t & 63;
  const int lr = lane & 15, lq = lane >> 4;
  const int rowbase = blockIdx.x * 64 + wave * 16;
  const int arow = rowbase + lr;

  f32x4 acc[8];
#pragma unroll
  for (int nt = 0; nt < 8; ++nt) acc[nt] = (f32x4){0.f, 0.f, 0.f, 0.f};

  const float* xrow = x + (size_t)arow * IN_DIM;
  const f16x8* wfv = reinterpret_cast<const f16x8*>(wf);
#pragma unroll
  for (int kc = 0; kc < 4; ++kc) {
    float4 lo = make_float4(0.f, 0.f, 0.f, 0.f), hi = lo;
    if (arow < N_NODES) {
      lo = *reinterpret_cast<const float4*>(xrow + kc * 32 + lq * 8);
      hi = *reinterpret_cast<const float4*>(xrow + kc * 32 + lq * 8 + 4);
    }
    f16x8 a;
    a[0] = (_Float16)lo.x; a[1] = (_Float16)lo.y; a[2] = (_Float16)lo.z; a[3] = (_Float16)lo.w;
    a[4] = (_Float16)hi.x; a[5] = (_Float16)hi.y; a[6] = (_Float16)hi.z; a[7] = (_Float16)hi.w;
    const f16x8* bbase = wfv + (size_t)(kc * 8) * 64 + lane;
#pragma unroll
    for (int nt = 0; nt < 8; ++nt) {
      f16x8 bfrag = bbase[nt * 64];
      acc[nt] = __builtin_amdgcn_mfma_f32_16x16x32_f16(a, bfrag, acc[nt], 0, 0, 0);
    }
  }

  // D layout: col = lane&15, row = (lane>>4)*4 + reg  [m89-verified]
  float as_lo[4], as_hi[4], ad_lo[4], ad_hi[4];
#pragma unroll
  for (int h = 0; h < 4; ++h) {
    as_lo[h] = as_v[h * HID + lr];      ad_lo[h] = ad_v[h * HID + lr];
    as_hi[h] = as_v[h * HID + 16 + lr]; ad_hi[h] = ad_v[h * HID + 16 + lr];
  }
#pragma unroll
  for (int nt = 0; nt < 8; ++nt) {
#pragma unroll
    for (int r = 0; r < 4; ++r) {
      int m = rowbase + lq * 4 + r;
      if (m < N_NODES) h1h[(size_t)m * D1 + nt * 16 + lr] = (_Float16)acc[nt][r];
    }
  }
#pragma unroll
  for (int h = 0; h < 4; ++h) {
#pragma unroll
    for (int r = 0; r < 4; ++r) {
      float ps = acc[2 * h][r] * as_lo[h] + acc[2 * h + 1][r] * as_hi[h];
      float pd = acc[2 * h][r] * ad_lo[h] + acc[2 * h + 1][r] * ad_hi[h];
#pragma unroll
      for (int off = 1; off < 16; off <<= 1) {
        ps += __shfl_xor(ps, off, 64);
        pd += __shfl_xor(pd, off, 64);
      }
      int m = rowbase + lq * 4 + r;
      if (lr == 0 && m < N_NODES) {
        asrc[m * HEADS + h] = ps;
        adst[m * HEADS + h] = pd;
      }
    }
  }
}

// ============ agg1: softmax (coefs in LDS) + fp16 gather + bias + relu ============
__global__ __launch_bounds__(256) void agg1(
    const int* __restrict__ row_off, const unsigned short* __restrict__ csr_src,
    const float* __restrict__ asrc, const float* __restrict__ adst,
    const __half* __restrict__ h1h, const float* __restrict__ b1,
    float* __restrict__ lbuf, float* __restrict__ z)
{
  __shared__ float cbuf[4][CAP * 4];
  const int w = threadIdx.x >> 6;
  int n = blockIdx.x * 4 + w;
  if (n >= N_NODES) return;
  const int lane = threadIdx.x & 63;
  const int start = row_off[n], end = row_off[n + 1];
  const bool useL = (end - start) <= CAP;
  float* cb = cbuf[w];
  const int h = lane & 3;
  const float adst_h = adst[n * HEADS + h];
  float vmax = -1e30f;
  for (int i = start + (lane >> 2); i < end; i += 16)
    vmax = fmaxf(vmax, asrc[(int)csr_src[i] * HEADS + h]);
#pragma unroll
  for (int off = 4; off < 64; off <<= 1)
    vmax = fmaxf(vmax, __shfl_xor(vmax, off, 64));
  float v = vmax + adst_h;
  const float mle = v > 0.f ? v : NEG_SLOPE * v;
  float ssum = 0.f;
  for (int i = start + (lane >> 2); i < end; i += 16) {
    float tv = asrc[(int)csr_src[i] * HEADS + h] + adst_h;
    float le = tv > 0.f ? tv : NEG_SLOPE * tv;
    float e = __expf(le - mle);
    if (useL) cb[(i - start) * 4 + h] = e;
    else      lbuf[(size_t)i * 4 + h] = e;
    ssum += e;
  }
#pragma unroll
  for (int off = 4; off < 64; off <<= 1)
    ssum += __shfl_xor(ssum, off, 64);
  const int hh = lane >> 4;
  const float inv = 1.f / __shfl(ssum, hh, 64);
  float2 acc = make_float2(0.f, 0.f);
  if (useL) {
    int i = start;
    for (; i + 8 <= end; i += 8) {
      float cc[8]; float2 vv[8];
#pragma unroll
      for (int u = 0; u < 8; ++u) {
        int s = csr_src[i + u];
        cc[u] = cb[(i + u - start) * 4 + hh];
        vv[u] = __half22float2(*(reinterpret_cast<const __half2*>(h1h + (size_t)s * D1) + lane));
      }
#pragma unroll
      for (int u = 0; u < 8; ++u) {
        acc.x += cc[u] * vv[u].x;
        acc.y += cc[u] * vv[u].y;
      }
    }
    for (; i < end; ++i) {
      int s = csr_src[i];
      float c = cb[(i - start) * 4 + hh];
      float2 hv = __half22float2(*(reinterpret_cast<const __half2*>(h1h + (size_t)s * D1) + lane));
      acc.x += c * hv.x;
      acc.y += c * hv.y;
    }
  } else {
    for (int i = start; i < end; ++i) {
      int s = csr_src[i];
      float c = lbuf[(size_t)i * 4 + hh];
      float2 hv = __half22float2(*(reinterpret_cast<const __half2*>(h1h + (size_t)s * D1) + lane));
      acc.x += c * hv.x;
      acc.y += c * hv.y;
    }
  }
  float2 bb = *reinterpret_cast<const float2*>(b1 + 2 * lane);
  float r0 = acc.x * inv + bb.x;
  float r1 = acc.y * inv + bb.y;
  float2 o = make_float2(r0 > 0.f ? r0 : 0.f, r1 > 0.f ? r1 : 0.f);
  *reinterpret_cast<float2*>(z + (size_t)n * D1 + 2 * lane) = o;
}

// ====== GEMM2: h2h = z @ W2 (fp16, padded rows of 64), W2 fully LDS-staged ======
__global__ __launch_bounds__(256) void gemm2(
    const float* __restrict__ z, const float* __restrict__ W2,
    const float* __restrict__ as2, const float* __restrict__ ad2,
    __half* __restrict__ h2h, float* __restrict__ asrc2, float* __restrict__ adst2)
{
  __shared__ float zs[32][IN_DIM];
  __shared__ float w2t[OUT_DIM][W2T_LD];
  const int nb = blockIdx.x * 32;
  const int t  = threadIdx.x;
  for (int i = t; i < 32 * (IN_DIM / 4); i += 256) {
    int r = i >> 5, k4 = (i & 31) * 4;
    int n = nb + r;
    float4 v = (n < N_NODES) ? *reinterpret_cast<const float4*>(z + (size_t)n * IN_DIM + k4)
                             : make_float4(0.f, 0.f, 0.f, 0.f);
    *reinterpret_cast<float4*>(&zs[r][k4]) = v;
  }
  for (int i = t; i < IN_DIM * OUT_DIM; i += 256) {
    int k = i / OUT_DIM, c = i - k * OUT_DIM;
    w2t[c][k] = W2[i];
  }
  __syncthreads();
  const int col = t & 63;
  const int rbase = (t >> 6) * 8;
  const bool valid = col < OUT_DIM;
  const int colc = valid ? col : (OUT_DIM - 1);
  float acc[8];
#pragma unroll
  for (int r = 0; r < 8; ++r) acc[r] = 0.f;
  for (int k = 0; k < IN_DIM; k += 4) {
    float4 wv = *reinterpret_cast<const float4*>(&w2t[colc][k]);
    float4 xv[8];
#pragma unroll
    for (int r = 0; r < 8; ++r)
      xv[r] = *reinterpret_cast<const float4*>(&zs[rbase + r][k]);
#pragma unroll
    for (int r = 0; r < 8; ++r)
      acc[r] += xv[r].x * wv.x + xv[r].y * wv.y + xv[r].z * wv.z + xv[r].w * wv.w;
  }
  const float a_s = valid ? as2[col] : 0.f;
  const float a_d = valid ? ad2[col] : 0.f;
#pragma unroll
  for (int r = 0; r < 8; ++r) {
    int n = nb + rbase + r;
    float cs = acc[r] * a_s, cd = acc[r] * a_d;
#pragma unroll
    for (int off = 32; off >= 1; off >>= 1) {
      cs += __shfl_xor(cs, off, 64);
      cd += __shfl_xor(cd, off, 64);
    }
    if (n < N_NODES) {
      if (valid) h2h[(size_t)n * H2P + col] = __float2half_rn(acc[r]);
      if (col == 0) { asrc2[n] = cs; adst2[n] = cd; }
    }
  }
}

// ============ agg2: softmax (coefs in LDS) + fp16 gather + b2 -> out ============
__global__ __launch_bounds__(256) void agg2(
    const int* __restrict__ row_off, const unsigned short* __restrict__ csr_src,
    const float* __restrict__ asrc, const float* __restrict__ adst,
    const __half* __restrict__ h2h, const float* __restrict__ b2,
    float* __restrict__ lbuf, float* __restrict__ out)
{
  __shared__ float cbuf[4][CAP];
  const int w = threadIdx.x >> 6;
  int n = blockIdx.x * 4 + w;
  if (n >= N_NODES) return;
  const int lane = threadIdx.x & 63;
  const int start = row_off[n], end = row_off[n + 1];
  const bool useL = (end - start) <= CAP;
  float* cb = cbuf[w];
  const float adstn = adst[n];
  float vmax = -1e30f;
  for (int i = start + lane; i < end; i += 64)
    vmax = fmaxf(vmax, asrc[csr_src[i]]);
#pragma unroll
  for (int off = 1; off < 64; off <<= 1)
    vmax = fmaxf(vmax, __shfl_xor(vmax, off, 64));
  float v = vmax + adstn;
  const float mle = v > 0.f ? v : NEG_SLOPE * v;
  float ssum = 0.f;
  for (int i = start + lane; i < end; i += 64) {
    float t = asrc[csr_src[i]] + adstn;
    float le = t > 0.f ? t : NEG_SLOPE * t;
    float e = __expf(le - mle);
    if (useL) cb[i - start] = e;
    else      lbuf[i] = e;
    ssum += e;
  }
#pragma unroll
  for (int off = 1; off < 64; off <<= 1)
    ssum += __shfl_xor(ssum, off, 64);
  const float inv = 1.f / ssum;
  if (lane < OUT_DIM) {
    float acc = 0.f;
    if (useL) {
      int i = start;
      for (; i + 8 <= end; i += 8) {
        float cc[8]; float vv[8];
#pragma unroll
        for (int u = 0; u < 8; ++u) {
          cc[u] = cb[i + u - start];
          vv[u] = __half2float(h2h[(size_t)csr_src[i + u] * H2P + lane]);
        }
#pragma unroll
        for (int u = 0; u < 8; ++u) acc += cc[u] * vv[u];
      }
      for (; i < end; ++i)
        acc += cb[i - start] * __half2float(h2h[(size_t)csr_src[i] * H2P + lane]);
    } else {
      for (int i = start; i < end; ++i)
        acc += lbuf[i] * __half2float(h2h[(size_t)csr_src[i] * H2P + lane]);
    }
    out[(size_t)n * OUT_DIM + lane] = acc * inv + b2[lane];
  }
}

// ================= launch =================
extern "C" void kernel_launch(void* const* d_in, const int* in_sizes, int n_in,
                              void* d_out, int out_size, void* d_ws, size_t ws_size,
                              hipStream_t stream)
{
  const float* x    = (const float*)d_in[0];
  const int*   ei   = (const int*)  d_in[1];
  const float* W1   = (const float*)d_in[2];
  const float* as1  = (const float*)d_in[3];
  const float* ad1  = (const float*)d_in[4];
  const float* b1   = (const float*)d_in[5];
  const float* W2   = (const float*)d_in[6];
  const float* as2  = (const float*)d_in[7];
  const float* ad2  = (const float*)d_in[8];
  const float* b2   = (const float*)d_in[9];
  float* out = (float*)d_out;

  float* ws = (float*)d_ws;
  _Float16* h1h = (_Float16*)(ws + 0);   // N*128 halves; h2h aliases
  __half*   h2h = (__half*)(ws + 0);     // N*64 halves, aliases dead h1h
  float* z     = ws +  6400000;  // N*128
  float* asrc1 = ws + 12800000;  // N*4
  float* adst1 = ws + 13000000;  // N*4
  float* asrc2 = ws + 13200000;  // N
  float* adst2 = ws + 13250000;  // N
  int* deg     = (int*)(ws + 13300000);  // N
  int* row_off = (int*)(ws + 13350000);  // N+1
  int* cursor  = (int*)(ws + 13410000);  // N
  unsigned short* csr_src = (unsigned short*)(ws + 13460000);  // E_TOT ushort
  int* blocksum= (int*)(ws + 14320000);  // SCAN_NB
  int* blockoff= (int*)(ws + 14320100);  // SCAN_NB
  float* lbuf  = ws + 14400000;  // E_TOT*4 fallback coef buffer
  _Float16* wf = (_Float16*)(ws + 17800000);  // 16384 halves = 32KB

  const int B = 256;
  // W repack (fp16 B-fragments) + deg zero, one fused launch
  init_wf_deg<<<64 + (N_NODES + B - 1) / B, B, 0, stream>>>(W1, wf, deg);
  count_deg<<<SCT_NB, B, 0, stream>>>(ei, deg);
  scan_p1<<<SCAN_NB, B, 0, stream>>>(deg, blocksum);
  scan_p2<<<1, 64, 0, stream>>>(blocksum, blockoff, row_off);
  scan_p3<<<SCAN_NB, B, 0, stream>>>(deg, blockoff, row_off, cursor);
  // layer-1 GEMM via MFMA, scatter_csr fused (independent halves of one launch)
  gemm1_mfma_scatter<<<GEMM1_NB + SCT_NB, B, 0, stream>>>(
      x, wf, as1, ad1, h1h, asrc1, adst1, ei, cursor, csr_src);
  // layer 1 aggregate
  agg1<<<(N_NODES + 3) / 4, B, 0, stream>>>(row_off, csr_src, asrc1, adst1,
                                            (const __half*)h1h, b1, lbuf, z);
  // layer 2 (h2h overwrites h1h — h1h is dead after agg1)
  gemm2<<<(N_NODES + 31) / 32, B, 0, stream>>>(z, W2, as2, ad2, h2h, asrc2, adst2);
  agg2<<<(N_NODES + 3) / 4, B, 0, stream>>>(row_off, csr_src, asrc2, adst2, h2h, b2, lbuf, out);
}